// Round 1
// baseline (620.675 us; speedup 1.0000x reference)
//
#include <hip/hip_runtime.h>
#include <stdint.h>

#define S_LEN 2048
#define BATCH 4
#define HID   2048
#define HD    128
#define NKV   4
#define KVLD  1024          // combined K|V projection row stride (2*NKV*HD)
#define MTOT  (BATCH*S_LEN) // 8192

typedef float  f32x4  __attribute__((ext_vector_type(4)));
typedef __bf16 bf16x8 __attribute__((ext_vector_type(8)));

// async global->LDS, 16B per lane. LDS dest = wave-uniform base + lane*16.
__device__ __forceinline__ void gld16(const void* g, void* l) {
    __builtin_amdgcn_global_load_lds(
        (const __attribute__((address_space(1))) void*)g,
        (__attribute__((address_space(3))) void*)l, 16, 0, 0);
}

// ---------------- fp32 -> bf16 bulk convert (8 elems/thread) ----------------
__global__ void k_conv_x(const float* __restrict__ in, __bf16* __restrict__ out) {
    int i = blockIdx.x * blockDim.x + threadIdx.x;
    f32x4 a = ((const f32x4*)in)[2 * i];
    f32x4 b = ((const f32x4*)in)[2 * i + 1];
    bf16x8 o;
    o[0] = (__bf16)a[0]; o[1] = (__bf16)a[1]; o[2] = (__bf16)a[2]; o[3] = (__bf16)a[3];
    o[4] = (__bf16)b[0]; o[5] = (__bf16)b[1]; o[6] = (__bf16)b[2]; o[7] = (__bf16)b[3];
    ((bf16x8*)out)[i] = o;
}

// ------------- W [K][N] fp32 -> Wt [N][K] bf16 (64x64 LDS tiles) ------------
__global__ void k_transpose_w(const float* __restrict__ in, __bf16* __restrict__ out,
                              int K, int N) {
    __shared__ float tile[64][65];
    int k0 = blockIdx.x * 64, n0 = blockIdx.y * 64;
    for (int e = threadIdx.x; e < 4096; e += 256) {
        int r = e >> 6, c = e & 63;
        tile[r][c] = in[(size_t)(k0 + r) * N + n0 + c];
    }
    __syncthreads();
    for (int e = threadIdx.x; e < 4096; e += 256) {
        int r = e >> 6, c = e & 63;
        out[(size_t)(n0 + r) * K + k0 + c] = (__bf16)tile[c][r];
    }
}

// -------- V slice of kvbuf [8192][1024] -> vt [16 planes][128 d][2048 s] ----
__global__ void k_transpose_v(const __bf16* __restrict__ kv, __bf16* __restrict__ vt) {
    __shared__ __bf16 tile[64][65];
    int plane = blockIdx.z;          // b*NKV + kvh
    int b = plane >> 2, kvh = plane & 3;
    int s0 = blockIdx.x * 64, d0 = blockIdx.y * 64;
    const __bf16* src = kv + (size_t)(b * S_LEN + s0) * KVLD + NKV * HD + kvh * HD + d0;
    for (int e = threadIdx.x; e < 4096; e += 256) {
        int r = e >> 6, c = e & 63;            // r: s offset, c: d offset
        tile[r][c] = src[(size_t)r * KVLD + c];
    }
    __syncthreads();
    __bf16* dst = vt + (size_t)plane * HD * S_LEN + (size_t)d0 * S_LEN + s0;
    for (int e = threadIdx.x; e < 4096; e += 256) {
        int r = e >> 6, c = e & 63;            // r: d offset, c: s offset
        dst[(size_t)r * S_LEN + c] = tile[c][r];
    }
}

// -------------------- RoPE (interleaved pairs) + optional scale -------------
__global__ void k_rope(__bf16* __restrict__ buf, const float* __restrict__ cosp,
                       const float* __restrict__ sinp, int ld, int ncol8, float scale) {
    int i = blockIdx.x * blockDim.x + threadIdx.x;
    int row = i / ncol8;
    int c0 = (i % ncol8) * 8;
    int s = row & (S_LEN - 1);
    int d0 = c0 & (HD - 1);
    __bf16* p = buf + (size_t)row * ld + c0;
    bf16x8 v = *(const bf16x8*)p;
    float f[8];
#pragma unroll
    for (int j = 0; j < 8; j++) f[j] = (float)v[j];
#pragma unroll
    for (int j = 0; j < 4; j++) {
        float c  = cosp[s * HD + d0 + 2 * j];
        float sn = sinp[s * HD + d0 + 2 * j];
        float e0 = f[2 * j], e1 = f[2 * j + 1];
        f[2 * j]     = (e0 * c - e1 * sn) * scale;
        f[2 * j + 1] = (e1 * c + e0 * sn) * scale;
    }
    bf16x8 o;
#pragma unroll
    for (int j = 0; j < 8; j++) o[j] = (__bf16)f[j];
    *(bf16x8*)p = o;
}

// --------------- GEMM: C[M][N] = A[M][K] * Bt[N][K]^T  (bf16 MFMA) ----------
// 128x128 tile, BK=64, 4 waves (2x2 of 64x64), T2 XOR-swizzled LDS.
template <bool OUTF32>
__global__ __launch_bounds__(256) void k_gemm(const __bf16* __restrict__ A,
                                              const __bf16* __restrict__ Bt,
                                              void* __restrict__ Cp,
                                              int M, int N, int K) {
    (void)M;
    __shared__ __bf16 As[128 * 64];
    __shared__ __bf16 Bs[128 * 64];
    const int tid = threadIdx.x, lane = tid & 63, wave = tid >> 6;
    const int wm = wave >> 1, wn = wave & 1;
    const int m0 = blockIdx.x * 128, n0 = blockIdx.y * 128;
    const int lo = lane & 15, hi = lane >> 4;
    f32x4 acc[4][4] = {};

    const int srow = wave * 8 + (lane >> 3); // staging row (+ r*32)
    const int sp   = lane & 7;               // physical 16B chunk

    for (int kt = 0; kt < K; kt += 64) {
#pragma unroll
        for (int r = 0; r < 4; r++) {        // A tile: rows of A, contiguous K
            int row = r * 32 + srow;
            int c = sp ^ (row & 7);          // inverse-swizzled source chunk
            gld16(A + (size_t)(m0 + row) * K + kt + c * 8, &As[(r * 32 + wave * 8) * 64]);
        }
#pragma unroll
        for (int r = 0; r < 4; r++) {        // B tile: rows of Bt (= cols of B)
            int row = r * 32 + srow;
            int c = sp ^ (row & 7);
            gld16(Bt + (size_t)(n0 + row) * K + kt + c * 8, &Bs[(r * 32 + wave * 8) * 64]);
        }
        __syncthreads();
#pragma unroll
        for (int ks = 0; ks < 2; ks++) {
            bf16x8 af[4], bfr[4];
#pragma unroll
            for (int mt = 0; mt < 4; mt++) {
                int row = wm * 64 + mt * 16 + lo;
                int pp = (ks * 4 + hi) ^ (row & 7);
                af[mt] = *(const bf16x8*)&As[row * 64 + pp * 8];
            }
#pragma unroll
            for (int nt = 0; nt < 4; nt++) {
                int row = wn * 64 + nt * 16 + lo;
                int pp = (ks * 4 + hi) ^ (row & 7);
                bfr[nt] = *(const bf16x8*)&Bs[row * 64 + pp * 8];
            }
#pragma unroll
            for (int mt = 0; mt < 4; mt++)
#pragma unroll
                for (int nt = 0; nt < 4; nt++)
                    acc[mt][nt] = __builtin_amdgcn_mfma_f32_16x16x32_bf16(
                        af[mt], bfr[nt], acc[mt][nt], 0, 0, 0);
        }
        __syncthreads();
    }
    // epilogue: C/D layout col=lane&15, row=(lane>>4)*4+reg
#pragma unroll
    for (int mt = 0; mt < 4; mt++) {
#pragma unroll
        for (int nt = 0; nt < 4; nt++) {
            int row = m0 + wm * 64 + mt * 16 + hi * 4;
            int col = n0 + wn * 64 + nt * 16 + lo;
#pragma unroll
            for (int r = 0; r < 4; r++) {
                if (OUTF32)
                    ((float*)Cp)[(size_t)(row + r) * N + col] = acc[mt][nt][r];
                else
                    ((__bf16*)Cp)[(size_t)(row + r) * N + col] = (__bf16)acc[mt][nt][r];
            }
        }
    }
}

// ----------------------------- flash attention ------------------------------
// grid (qtile=32, head=16, batch=4); 4 waves x 16 q-rows; KVBLK=64; GQA /4.
__global__ __launch_bounds__(256) void k_attn(const __bf16* __restrict__ qb,
                                              const __bf16* __restrict__ kb,
                                              const __bf16* __restrict__ vtb,
                                              __bf16* __restrict__ ob) {
    __shared__ __bf16 Ks[64 * 128];   // [kv][d]
    __shared__ __bf16 Vs[128 * 64];   // [d][kv]
    __shared__ __bf16 Ps[4][16 * 64]; // per-wave P
    const int tid = threadIdx.x, lane = tid & 63, wave = tid >> 6;
    const int qt = blockIdx.x, h = blockIdx.y, b = blockIdx.z;
    const int kvh = h >> 2;
    const int lo = lane & 15, hi = lane >> 4;

    // Q fragments (q is pre-scaled by 1/sqrt(HD) in k_rope)
    const int qrow = qt * 64 + wave * 16 + lo;
    const __bf16* qptr = qb + (size_t)(b * S_LEN + qrow) * HID + h * HD;
    bf16x8 qa[4];
#pragma unroll
    for (int kf = 0; kf < 4; kf++) qa[kf] = *(const bf16x8*)(qptr + kf * 32 + hi * 8);

    f32x4 o[8] = {};
    float Mr[4] = {-1e30f, -1e30f, -1e30f, -1e30f};
    float Lr[4] = {0.f, 0.f, 0.f, 0.f};

    const int krow_s = wave * 4 + hi;          // K stage row (+ r*16)
    const int kp_s   = lane & 15;
    const int vrow_s = wave * 8 + (lane >> 3); // V stage row (+ r*32)
    const int vp_s   = lane & 7;

    for (int t = 0; t <= qt; t++) {
        __syncthreads(); // prior tile's LDS reads done before restaging
#pragma unroll
        for (int r = 0; r < 4; r++) { // K tile [64][128], 16 chunks/row
            int row = r * 16 + krow_s;
            int c = kp_s ^ (row & 7);
            gld16(kb + (size_t)(b * S_LEN + t * 64 + row) * KVLD + kvh * HD + c * 8,
                  &Ks[(r * 16 + wave * 4) * 128]);
        }
#pragma unroll
        for (int r = 0; r < 4; r++) { // Vt tile [128][64], 8 chunks/row
            int row = r * 32 + vrow_s;
            int c = vp_s ^ (row & 7);
            gld16(vtb + (size_t)(b * NKV + kvh) * HD * S_LEN + (size_t)row * S_LEN + t * 64 + c * 8,
                  &Vs[(r * 32 + wave * 8) * 64]);
        }
        __syncthreads();

        // S = Q K^T  (rows = q, cols = kv)
        f32x4 sc[4];
#pragma unroll
        for (int nt = 0; nt < 4; nt++) {
            f32x4 s4 = {0.f, 0.f, 0.f, 0.f};
#pragma unroll
            for (int kf = 0; kf < 4; kf++) {
                int row = nt * 16 + lo;
                int pp = (kf * 4 + hi) ^ (row & 7);
                bf16x8 kf8 = *(const bf16x8*)&Ks[row * 128 + pp * 8];
                s4 = __builtin_amdgcn_mfma_f32_16x16x32_bf16(qa[kf], kf8, s4, 0, 0, 0);
            }
            sc[nt] = s4;
        }
        if (t == qt) { // causal mask on diagonal tile
#pragma unroll
            for (int nt = 0; nt < 4; nt++)
#pragma unroll
                for (int r = 0; r < 4; r++) {
                    int qg = qt * 64 + wave * 16 + hi * 4 + r;
                    int kg = t * 64 + nt * 16 + lo;
                    if (kg > qg) sc[nt][r] = -1e30f;
                }
        }
        // online softmax (fp32); row m = hi*4+r lives in a 16-lane group
        float p[4][4];
#pragma unroll
        for (int r = 0; r < 4; r++) {
            float m = fmaxf(fmaxf(sc[0][r], sc[1][r]), fmaxf(sc[2][r], sc[3][r]));
#pragma unroll
            for (int msk = 1; msk < 16; msk <<= 1) m = fmaxf(m, __shfl_xor(m, msk, 64));
            float mn = fmaxf(Mr[r], m);
            float sum = 0.f;
#pragma unroll
            for (int nt = 0; nt < 4; nt++) {
                float e = __expf(sc[nt][r] - mn);
                p[nt][r] = e;
                sum += e;
            }
#pragma unroll
            for (int msk = 1; msk < 16; msk <<= 1) sum += __shfl_xor(sum, msk, 64);
            float scl = __expf(Mr[r] - mn);
            Lr[r] = Lr[r] * scl + sum;
            Mr[r] = mn;
#pragma unroll
            for (int dt = 0; dt < 8; dt++) o[dt][r] *= scl;
        }
        // P (C-layout) -> wave-private swizzled LDS -> A-fragments
#pragma unroll
        for (int nt = 0; nt < 4; nt++)
#pragma unroll
            for (int r = 0; r < 4; r++) {
                int m = hi * 4 + r;
                int n = nt * 16 + lo;
                int pp = (n >> 3) ^ (m & 7);
                Ps[wave][m * 64 + pp * 8 + (n & 7)] = (__bf16)p[nt][r];
            }
        asm volatile("s_waitcnt lgkmcnt(0)" ::: "memory");
        // O += P V
#pragma unroll
        for (int dt = 0; dt < 8; dt++) {
#pragma unroll
            for (int sub = 0; sub < 2; sub++) {
                int ch = sub * 4 + hi;
                bf16x8 pa = *(const bf16x8*)&Ps[wave][lo * 64 + (ch ^ (lo & 7)) * 8];
                int rowd = dt * 16 + lo;
                bf16x8 vv = *(const bf16x8*)&Vs[rowd * 64 + (ch ^ (rowd & 7)) * 8];
                o[dt] = __builtin_amdgcn_mfma_f32_16x16x32_bf16(pa, vv, o[dt], 0, 0, 0);
            }
        }
    }
    // epilogue: write O / L as bf16 into [b*S+q][h*HD+d]
#pragma unroll
    for (int dt = 0; dt < 8; dt++)
#pragma unroll
        for (int r = 0; r < 4; r++) {
            int qg = qt * 64 + wave * 16 + hi * 4 + r;
            int col = h * HD + dt * 16 + lo;
            ob[(size_t)(b * S_LEN + qg) * HID + col] = (__bf16)(o[dt][r] / Lr[r]);
        }
}

// ----------------------------------- host -----------------------------------
extern "C" void kernel_launch(void* const* d_in, const int* in_sizes, int n_in,
                              void* d_out, int out_size, void* d_ws, size_t ws_size,
                              hipStream_t stream) {
    (void)in_sizes; (void)n_in; (void)out_size; (void)ws_size;
    const float* x    = (const float*)d_in[0];
    const float* cosp = (const float*)d_in[1];
    const float* sinp = (const float*)d_in[2];
    const float* Wq   = (const float*)d_in[3];
    const float* Wk   = (const float*)d_in[4];
    const float* Wv   = (const float*)d_in[5];
    const float* Wo   = (const float*)d_in[6];
    float* out = (float*)d_out;

    char* ws = (char*)d_ws;
    __bf16* xb   = (__bf16*)(ws);                 // [8192][2048]        32 MB
    __bf16* wqt  = (__bf16*)(ws + 33554432);      // [2048][2048]         8 MB
    __bf16* wkvt = (__bf16*)(ws + 41943040);      // [1024][2048] (k|v)   4 MB
    __bf16* wot  = (__bf16*)(ws + 46137344);      // [2048][2048]         8 MB
    __bf16* qbuf = (__bf16*)(ws + 54525952);      // [8192][2048]        32 MB
    __bf16* kv   = (__bf16*)(ws + 88080384);      // [8192][1024]        16 MB
    __bf16* vtb  = (__bf16*)(ws + 104857600);     // [16][128][2048]      8 MB
    __bf16* aob  = xb;                            // reuse xb after QKV GEMMs

    k_conv_x<<<MTOT * HID / 8 / 256, 256, 0, stream>>>(x, xb);
    { dim3 g(32, 32); k_transpose_w<<<g, 256, 0, stream>>>(Wq, wqt, HID, HID); }
    { dim3 g(32, 8);  k_transpose_w<<<g, 256, 0, stream>>>(Wk, wkvt, HID, NKV * HD); }
    { dim3 g(32, 8);  k_transpose_w<<<g, 256, 0, stream>>>(Wv, wkvt + (size_t)512 * HID, HID, NKV * HD); }
    { dim3 g(32, 32); k_transpose_w<<<g, 256, 0, stream>>>(Wo, wot, HID, HID); }

    { dim3 g(MTOT / 128, HID / 128);  k_gemm<false><<<g, 256, 0, stream>>>(xb, wqt,  qbuf, MTOT, HID,  HID); }
    { dim3 g(MTOT / 128, KVLD / 128); k_gemm<false><<<g, 256, 0, stream>>>(xb, wkvt, kv,   MTOT, KVLD, HID); }

    k_rope<<<MTOT * HID / 8 / 256, 256, 0, stream>>>(qbuf, cosp, sinp, HID, HID / 8,
                                                     0.08838834764831845f); // 1/sqrt(128)
    k_rope<<<MTOT * 512 / 8 / 256, 256, 0, stream>>>(kv, cosp, sinp, KVLD, 512 / 8, 1.0f);

    { dim3 g(S_LEN / 64, HD / 64, 16); k_transpose_v<<<g, 256, 0, stream>>>(kv, vtb); }
    { dim3 g(S_LEN / 64, 16, BATCH);   k_attn<<<g, 256, 0, stream>>>(qbuf, kv, vtb, aob); }
    { dim3 g(MTOT / 128, HID / 128);   k_gemm<true><<<g, 256, 0, stream>>>(aob, wot, out, MTOT, HID, HID); }
}

// Round 2
// 512.457 us; speedup vs baseline: 1.2112x; 1.2112x over previous
//
#include <hip/hip_runtime.h>
#include <stdint.h>

#define S_LEN 2048
#define BATCH 4
#define HID   2048
#define HD    128
#define NKV   4
#define KVLD  1024          // combined K|V projection row stride (2*NKV*HD)
#define MTOT  (BATCH*S_LEN) // 8192
#define NT    (S_LEN/64)    // 32 q-tiles per (b,h)

typedef float  f32x4  __attribute__((ext_vector_type(4)));
typedef __bf16 bf16x8 __attribute__((ext_vector_type(8)));

// async global->LDS, 16B per lane. LDS dest = wave-uniform base + lane*16.
__device__ __forceinline__ void gld16(const void* g, void* l) {
    __builtin_amdgcn_global_load_lds(
        (const __attribute__((address_space(1))) void*)g,
        (__attribute__((address_space(3))) void*)l, 16, 0, 0);
}

// ---------------- fp32 -> bf16 bulk convert (8 elems/thread) ----------------
__global__ void k_conv_x(const float* __restrict__ in, __bf16* __restrict__ out) {
    int i = blockIdx.x * blockDim.x + threadIdx.x;
    f32x4 a = ((const f32x4*)in)[2 * i];
    f32x4 b = ((const f32x4*)in)[2 * i + 1];
    bf16x8 o;
    o[0] = (__bf16)a[0]; o[1] = (__bf16)a[1]; o[2] = (__bf16)a[2]; o[3] = (__bf16)a[3];
    o[4] = (__bf16)b[0]; o[5] = (__bf16)b[1]; o[6] = (__bf16)b[2]; o[7] = (__bf16)b[3];
    ((bf16x8*)out)[i] = o;
}

// ------------- W [K][N] fp32 -> Wt [N][K] bf16 (64x64 LDS tiles) ------------
__global__ void k_transpose_w(const float* __restrict__ in, __bf16* __restrict__ out,
                              int K, int N) {
    __shared__ float tile[64][65];
    int k0 = blockIdx.x * 64, n0 = blockIdx.y * 64;
    for (int e = threadIdx.x; e < 4096; e += 256) {
        int r = e >> 6, c = e & 63;
        tile[r][c] = in[(size_t)(k0 + r) * N + n0 + c];
    }
    __syncthreads();
    for (int e = threadIdx.x; e < 4096; e += 256) {
        int r = e >> 6, c = e & 63;
        out[(size_t)(n0 + r) * K + k0 + c] = (__bf16)tile[c][r];
    }
}

// -------- V slice of kvbuf [8192][1024] -> vt [16 planes][128 d][2048 s] ----
__global__ void k_transpose_v(const __bf16* __restrict__ kv, __bf16* __restrict__ vt) {
    __shared__ __bf16 tile[64][65];
    int plane = blockIdx.z;          // b*NKV + kvh
    int b = plane >> 2, kvh = plane & 3;
    int s0 = blockIdx.x * 64, d0 = blockIdx.y * 64;
    const __bf16* src = kv + (size_t)(b * S_LEN + s0) * KVLD + NKV * HD + kvh * HD + d0;
    for (int e = threadIdx.x; e < 4096; e += 256) {
        int r = e >> 6, c = e & 63;            // r: s offset, c: d offset
        tile[r][c] = src[(size_t)r * KVLD + c];
    }
    __syncthreads();
    __bf16* dst = vt + (size_t)plane * HD * S_LEN + (size_t)d0 * S_LEN + s0;
    for (int e = threadIdx.x; e < 4096; e += 256) {
        int r = e >> 6, c = e & 63;            // r: d offset, c: s offset
        dst[(size_t)r * S_LEN + c] = tile[c][r];
    }
}

// -------------------- RoPE (interleaved pairs) + optional scale -------------
__global__ void k_rope(__bf16* __restrict__ buf, const float* __restrict__ cosp,
                       const float* __restrict__ sinp, int ld, int ncol8, float scale) {
    int i = blockIdx.x * blockDim.x + threadIdx.x;
    int row = i / ncol8;
    int c0 = (i % ncol8) * 8;
    int s = row & (S_LEN - 1);
    int d0 = c0 & (HD - 1);
    __bf16* p = buf + (size_t)row * ld + c0;
    bf16x8 v = *(const bf16x8*)p;
    float f[8];
#pragma unroll
    for (int j = 0; j < 8; j++) f[j] = (float)v[j];
#pragma unroll
    for (int j = 0; j < 4; j++) {
        float c  = cosp[s * HD + d0 + 2 * j];
        float sn = sinp[s * HD + d0 + 2 * j];
        float e0 = f[2 * j], e1 = f[2 * j + 1];
        f[2 * j]     = (e0 * c - e1 * sn) * scale;
        f[2 * j + 1] = (e1 * c + e0 * sn) * scale;
    }
    bf16x8 o;
#pragma unroll
    for (int j = 0; j < 8; j++) o[j] = (__bf16)f[j];
    *(bf16x8*)p = o;
}

// --------------- GEMM: C[M][N] = A[M][K] * Bt[N][K]^T  (bf16 MFMA) ----------
// 128x128 tile, BK=64, 4 waves (2x2 of 64x64), T2 XOR-swizzled LDS.
template <bool OUTF32>
__global__ __launch_bounds__(256) void k_gemm(const __bf16* __restrict__ A,
                                              const __bf16* __restrict__ Bt,
                                              void* __restrict__ Cp,
                                              int M, int N, int K) {
    (void)M;
    __shared__ __bf16 As[128 * 64];
    __shared__ __bf16 Bs[128 * 64];
    const int tid = threadIdx.x, lane = tid & 63, wave = tid >> 6;
    const int wm = wave >> 1, wn = wave & 1;
    const int m0 = blockIdx.x * 128, n0 = blockIdx.y * 128;
    const int lo = lane & 15, hi = lane >> 4;
    f32x4 acc[4][4] = {};

    const int srow = wave * 8 + (lane >> 3); // staging row (+ r*32)
    const int sp   = lane & 7;               // physical 16B chunk

    for (int kt = 0; kt < K; kt += 64) {
#pragma unroll
        for (int r = 0; r < 4; r++) {        // A tile: rows of A, contiguous K
            int row = r * 32 + srow;
            int c = sp ^ (row & 7);          // inverse-swizzled source chunk
            gld16(A + (size_t)(m0 + row) * K + kt + c * 8, &As[(r * 32 + wave * 8) * 64]);
        }
#pragma unroll
        for (int r = 0; r < 4; r++) {        // B tile: rows of Bt (= cols of B)
            int row = r * 32 + srow;
            int c = sp ^ (row & 7);
            gld16(Bt + (size_t)(n0 + row) * K + kt + c * 8, &Bs[(r * 32 + wave * 8) * 64]);
        }
        __syncthreads();
#pragma unroll
        for (int ks = 0; ks < 2; ks++) {
            bf16x8 af[4], bfr[4];
#pragma unroll
            for (int mt = 0; mt < 4; mt++) {
                int row = wm * 64 + mt * 16 + lo;
                int pp = (ks * 4 + hi) ^ (row & 7);
                af[mt] = *(const bf16x8*)&As[row * 64 + pp * 8];
            }
#pragma unroll
            for (int nt = 0; nt < 4; nt++) {
                int row = wn * 64 + nt * 16 + lo;
                int pp = (ks * 4 + hi) ^ (row & 7);
                bfr[nt] = *(const bf16x8*)&Bs[row * 64 + pp * 8];
            }
#pragma unroll
            for (int mt = 0; mt < 4; mt++)
#pragma unroll
                for (int nt = 0; nt < 4; nt++)
                    acc[mt][nt] = __builtin_amdgcn_mfma_f32_16x16x32_bf16(
                        af[mt], bfr[nt], acc[mt][nt], 0, 0, 0);
        }
        __syncthreads();
    }
    // epilogue: C/D layout col=lane&15, row=(lane>>4)*4+reg
#pragma unroll
    for (int mt = 0; mt < 4; mt++) {
#pragma unroll
        for (int nt = 0; nt < 4; nt++) {
            int row = m0 + wm * 64 + mt * 16 + hi * 4;
            int col = n0 + wn * 64 + nt * 16 + lo;
#pragma unroll
            for (int r = 0; r < 4; r++) {
                if (OUTF32)
                    ((float*)Cp)[(size_t)(row + r) * N + col] = acc[mt][nt][r];
                else
                    ((__bf16*)Cp)[(size_t)(row + r) * N + col] = (__bf16)acc[mt][nt][r];
            }
        }
    }
}

// ----------------------------- flash attention ------------------------------
// grid (pair=16, head=16, batch=4); each block does q-tiles {pair, 31-pair}
// -> uniform 33 kv-tile iterations per block (causal balance fix).
// 4 waves x 16 q-rows; KVBLK=64; GQA /4; double-buffered K/V LDS (2-phase).
__global__ __launch_bounds__(256) void k_attn(const __bf16* __restrict__ qb,
                                              const __bf16* __restrict__ kb,
                                              const __bf16* __restrict__ vtb,
                                              __bf16* __restrict__ ob) {
    __shared__ __bf16 Ks[2][64 * 128];   // [kv][d]
    __shared__ __bf16 Vs[2][128 * 64];   // [d][kv]
    __shared__ __bf16 Ps[4][16 * 64];    // per-wave P
    const int tid = threadIdx.x, lane = tid & 63, wave = tid >> 6;
    const int pair = blockIdx.x, h = blockIdx.y, b = blockIdx.z;
    const int kvh = h >> 2;
    const int lo = lane & 15, hi = lane >> 4;

    const int krow_s = wave * 4 + hi;          // K stage row (+ r*16)
    const int kp_s   = lane & 15;
    const int vrow_s = wave * 8 + (lane >> 3); // V stage row (+ r*32)
    const int vp_s   = lane & 7;

    const __bf16* kbb = kb + kvh * HD + (size_t)b * S_LEN * KVLD;
    const __bf16* vbb = vtb + (size_t)(b * NKV + kvh) * HD * S_LEN;

    auto STAGE = [&](int buf, int t) {
#pragma unroll
        for (int r = 0; r < 4; r++) {          // K tile [64][128], 16 chunks/row
            int row = r * 16 + krow_s;
            int c = kp_s ^ (row & 7);
            gld16(kbb + (size_t)(t * 64 + row) * KVLD + c * 8,
                  &Ks[buf][(r * 16 + wave * 4) * 128]);
        }
#pragma unroll
        for (int r = 0; r < 4; r++) {          // Vt tile [128][64], 8 chunks/row
            int row = r * 32 + vrow_s;
            int c = vp_s ^ (row & 7);
            gld16(vbb + (size_t)row * S_LEN + t * 64 + c * 8,
                  &Vs[buf][(r * 32 + wave * 8) * 64]);
        }
    };

#pragma unroll 1
    for (int pi = 0; pi < 2; pi++) {
        const int qt = pi ? (NT - 1 - pair) : pair;

        // Q fragments (q is pre-scaled by 1/sqrt(HD) in k_rope)
        const int qrow = qt * 64 + wave * 16 + lo;
        const __bf16* qptr = qb + (size_t)(b * S_LEN + qrow) * HID + h * HD;
        bf16x8 qa[4];
#pragma unroll
        for (int kf = 0; kf < 4; kf++) qa[kf] = *(const bf16x8*)(qptr + kf * 32 + hi * 8);

        f32x4 o[8] = {};
        float Mr[4] = {-3e30f, -3e30f, -3e30f, -3e30f};
        float Lr[4] = {0.f, 0.f, 0.f, 0.f};

        int cur = 0;
        STAGE(0, 0);
        __syncthreads();   // drains stage-0 loads (compiler vmcnt(0) at barrier)

#pragma unroll 1
        for (int t = 0; t <= qt; t++) {
            if (t < qt) STAGE(cur ^ 1, t + 1);  // prefetch next tile, hides HBM latency

            // S = Q K^T  (rows = q, cols = kv)
            f32x4 sc[4];
#pragma unroll
            for (int nt = 0; nt < 4; nt++) {
                f32x4 s4 = {0.f, 0.f, 0.f, 0.f};
#pragma unroll
                for (int kf = 0; kf < 4; kf++) {
                    int row = nt * 16 + lo;
                    int pp = (kf * 4 + hi) ^ (row & 7);
                    bf16x8 kf8 = *(const bf16x8*)&Ks[cur][row * 128 + pp * 8];
                    s4 = __builtin_amdgcn_mfma_f32_16x16x32_bf16(qa[kf], kf8, s4, 0, 0, 0);
                }
                sc[nt] = s4;
            }
            if (t == qt) { // causal mask on diagonal tile
#pragma unroll
                for (int nt = 0; nt < 4; nt++)
#pragma unroll
                    for (int r = 0; r < 4; r++) {
                        int qg = qt * 64 + wave * 16 + hi * 4 + r;
                        int kg = t * 64 + nt * 16 + lo;
                        if (kg > qg) sc[nt][r] = -1e30f;
                    }
            }
            // online softmax (fp32); row m = hi*4+r lives in a 16-lane group.
            // T13 defer-max: keep old running max if growth <= 8 (P bounded e^8).
            float p[4][4];
#pragma unroll
            for (int r = 0; r < 4; r++) {
                float m = fmaxf(fmaxf(sc[0][r], sc[1][r]), fmaxf(sc[2][r], sc[3][r]));
#pragma unroll
                for (int msk = 1; msk < 16; msk <<= 1) m = fmaxf(m, __shfl_xor(m, msk, 64));
                float mn = (m <= Mr[r] + 8.f) ? Mr[r] : m;
                float sum = 0.f;
#pragma unroll
                for (int nt = 0; nt < 4; nt++) {
                    float e = __expf(sc[nt][r] - mn);
                    p[nt][r] = e;
                    sum += e;
                }
#pragma unroll
                for (int msk = 1; msk < 16; msk <<= 1) sum += __shfl_xor(sum, msk, 64);
                if (mn != Mr[r]) {
                    float scl = __expf(Mr[r] - mn);
                    Lr[r] = Lr[r] * scl + sum;
                    Mr[r] = mn;
#pragma unroll
                    for (int dt = 0; dt < 8; dt++) o[dt][r] *= scl;
                } else {
                    Lr[r] += sum;
                }
            }
            // P (C-layout) -> wave-private swizzled LDS -> A-fragments
#pragma unroll
            for (int nt = 0; nt < 4; nt++)
#pragma unroll
                for (int r = 0; r < 4; r++) {
                    int m = hi * 4 + r;
                    int n = nt * 16 + lo;
                    int pp = (n >> 3) ^ (m & 7);
                    Ps[wave][m * 64 + pp * 8 + (n & 7)] = (__bf16)p[nt][r];
                }
            asm volatile("s_waitcnt lgkmcnt(0)" ::: "memory");
            // O += P V   (pa invariant across dt: hoist the 2 reads)
            bf16x8 pa[2];
#pragma unroll
            for (int sub = 0; sub < 2; sub++) {
                int ch = sub * 4 + hi;
                pa[sub] = *(const bf16x8*)&Ps[wave][lo * 64 + (ch ^ (lo & 7)) * 8];
            }
#pragma unroll
            for (int dt = 0; dt < 8; dt++) {
#pragma unroll
                for (int sub = 0; sub < 2; sub++) {
                    int ch = sub * 4 + hi;
                    int rowd = dt * 16 + lo;
                    bf16x8 vv = *(const bf16x8*)&Vs[cur][rowd * 64 + (ch ^ (rowd & 7)) * 8];
                    o[dt] = __builtin_amdgcn_mfma_f32_16x16x32_bf16(pa[sub], vv, o[dt], 0, 0, 0);
                }
            }
            __syncthreads();  // drains prefetch; protects K/V bufs before reuse
            cur ^= 1;
        }
        // epilogue: write O / L as bf16 into [b*S+q][h*HD+d]
        float rl[4];
#pragma unroll
        for (int r = 0; r < 4; r++) rl[r] = 1.0f / Lr[r];
#pragma unroll
        for (int dt = 0; dt < 8; dt++)
#pragma unroll
            for (int r = 0; r < 4; r++) {
                int qg = qt * 64 + wave * 16 + hi * 4 + r;
                int col = h * HD + dt * 16 + lo;
                ob[(size_t)(b * S_LEN + qg) * HID + col] = (__bf16)(o[dt][r] * rl[r]);
            }
    }
}

// ----------------------------------- host -----------------------------------
extern "C" void kernel_launch(void* const* d_in, const int* in_sizes, int n_in,
                              void* d_out, int out_size, void* d_ws, size_t ws_size,
                              hipStream_t stream) {
    (void)in_sizes; (void)n_in; (void)out_size; (void)ws_size;
    const float* x    = (const float*)d_in[0];
    const float* cosp = (const float*)d_in[1];
    const float* sinp = (const float*)d_in[2];
    const float* Wq   = (const float*)d_in[3];
    const float* Wk   = (const float*)d_in[4];
    const float* Wv   = (const float*)d_in[5];
    const float* Wo   = (const float*)d_in[6];
    float* out = (float*)d_out;

    char* ws = (char*)d_ws;
    __bf16* xb   = (__bf16*)(ws);                 // [8192][2048]        32 MB
    __bf16* wqt  = (__bf16*)(ws + 33554432);      // [2048][2048]         8 MB
    __bf16* wkvt = (__bf16*)(ws + 41943040);      // [1024][2048] (k|v)   4 MB
    __bf16* wot  = (__bf16*)(ws + 46137344);      // [2048][2048]         8 MB
    __bf16* qbuf = (__bf16*)(ws + 54525952);      // [8192][2048]        32 MB
    __bf16* kv   = (__bf16*)(ws + 88080384);      // [8192][1024]        16 MB
    __bf16* vtb  = (__bf16*)(ws + 104857600);     // [16][128][2048]      8 MB
    __bf16* aob  = xb;                            // reuse xb after QKV GEMMs

    k_conv_x<<<MTOT * HID / 8 / 256, 256, 0, stream>>>(x, xb);
    { dim3 g(32, 32); k_transpose_w<<<g, 256, 0, stream>>>(Wq, wqt, HID, HID); }
    { dim3 g(32, 8);  k_transpose_w<<<g, 256, 0, stream>>>(Wk, wkvt, HID, NKV * HD); }
    { dim3 g(32, 8);  k_transpose_w<<<g, 256, 0, stream>>>(Wv, wkvt + (size_t)512 * HID, HID, NKV * HD); }
    { dim3 g(32, 32); k_transpose_w<<<g, 256, 0, stream>>>(Wo, wot, HID, HID); }

    { dim3 g(MTOT / 128, HID / 128);  k_gemm<false><<<g, 256, 0, stream>>>(xb, wqt,  qbuf, MTOT, HID,  HID); }
    { dim3 g(MTOT / 128, KVLD / 128); k_gemm<false><<<g, 256, 0, stream>>>(xb, wkvt, kv,   MTOT, KVLD, HID); }

    k_rope<<<MTOT * HID / 8 / 256, 256, 0, stream>>>(qbuf, cosp, sinp, HID, HID / 8,
                                                     0.08838834764831845f); // 1/sqrt(128)
    k_rope<<<MTOT * 512 / 8 / 256, 256, 0, stream>>>(kv, cosp, sinp, KVLD, 512 / 8, 1.0f);

    { dim3 g(S_LEN / 64, HD / 64, 16); k_transpose_v<<<g, 256, 0, stream>>>(kv, vtb); }
    { dim3 g(NT / 2, 16, BATCH);       k_attn<<<g, 256, 0, stream>>>(qbuf, kv, vtb, aob); }
    { dim3 g(MTOT / 128, HID / 128);   k_gemm<true><<<g, 256, 0, stream>>>(aob, wot, out, MTOT, HID, HID); }
}

// Round 3
// 504.908 us; speedup vs baseline: 1.2293x; 1.0150x over previous
//
#include <hip/hip_runtime.h>
#include <stdint.h>

#define S_LEN 2048
#define BATCH 4
#define HID   2048
#define HD    128
#define NKV   4
#define KVLD  1024          // combined K|V projection row stride (2*NKV*HD)
#define MTOT  (BATCH*S_LEN) // 8192
#define NQT   (S_LEN/128)   // 16 q-tiles (128 rows) per (b,h)

typedef float  f32x4  __attribute__((ext_vector_type(4)));
typedef __bf16 bf16x8 __attribute__((ext_vector_type(8)));

// async global->LDS, 16B per lane. LDS dest = wave-uniform base + lane*16.
__device__ __forceinline__ void gld16(const void* g, void* l) {
    __builtin_amdgcn_global_load_lds(
        (const __attribute__((address_space(1))) void*)g,
        (__attribute__((address_space(3))) void*)l, 16, 0, 0);
}

// ---------------- fp32 -> bf16 bulk convert (8 elems/thread) ----------------
__global__ void k_conv_x(const float* __restrict__ in, __bf16* __restrict__ out) {
    int i = blockIdx.x * blockDim.x + threadIdx.x;
    f32x4 a = ((const f32x4*)in)[2 * i];
    f32x4 b = ((const f32x4*)in)[2 * i + 1];
    bf16x8 o;
    o[0] = (__bf16)a[0]; o[1] = (__bf16)a[1]; o[2] = (__bf16)a[2]; o[3] = (__bf16)a[3];
    o[4] = (__bf16)b[0]; o[5] = (__bf16)b[1]; o[6] = (__bf16)b[2]; o[7] = (__bf16)b[3];
    ((bf16x8*)out)[i] = o;
}

// ------------- W [K][N] fp32 -> Wt [N][K] bf16 (64x64 LDS tiles) ------------
__global__ void k_transpose_w(const float* __restrict__ in, __bf16* __restrict__ out,
                              int K, int N) {
    __shared__ float tile[64][65];
    int k0 = blockIdx.x * 64, n0 = blockIdx.y * 64;
    for (int e = threadIdx.x; e < 4096; e += 256) {
        int r = e >> 6, c = e & 63;
        tile[r][c] = in[(size_t)(k0 + r) * N + n0 + c];
    }
    __syncthreads();
    for (int e = threadIdx.x; e < 4096; e += 256) {
        int r = e >> 6, c = e & 63;
        out[(size_t)(n0 + r) * K + k0 + c] = (__bf16)tile[c][r];
    }
}

// -------- V slice of kvbuf [8192][1024] -> vt [16 planes][128 d][2048 s] ----
__global__ void k_transpose_v(const __bf16* __restrict__ kv, __bf16* __restrict__ vt) {
    __shared__ __bf16 tile[64][65];
    int plane = blockIdx.z;          // b*NKV + kvh
    int b = plane >> 2, kvh = plane & 3;
    int s0 = blockIdx.x * 64, d0 = blockIdx.y * 64;
    const __bf16* src = kv + (size_t)(b * S_LEN + s0) * KVLD + NKV * HD + kvh * HD + d0;
    for (int e = threadIdx.x; e < 4096; e += 256) {
        int r = e >> 6, c = e & 63;            // r: s offset, c: d offset
        tile[r][c] = src[(size_t)r * KVLD + c];
    }
    __syncthreads();
    __bf16* dst = vt + (size_t)plane * HD * S_LEN + (size_t)d0 * S_LEN + s0;
    for (int e = threadIdx.x; e < 4096; e += 256) {
        int r = e >> 6, c = e & 63;            // r: d offset, c: s offset
        dst[(size_t)r * S_LEN + c] = tile[c][r];
    }
}

// -------------------- RoPE (interleaved pairs) + optional scale -------------
__global__ void k_rope(__bf16* __restrict__ buf, const float* __restrict__ cosp,
                       const float* __restrict__ sinp, int ld, int ncol8, float scale) {
    int i = blockIdx.x * blockDim.x + threadIdx.x;
    int row = i / ncol8;
    int c0 = (i % ncol8) * 8;
    int s = row & (S_LEN - 1);
    int d0 = c0 & (HD - 1);
    __bf16* p = buf + (size_t)row * ld + c0;
    bf16x8 v = *(const bf16x8*)p;
    float f[8];
#pragma unroll
    for (int j = 0; j < 8; j++) f[j] = (float)v[j];
#pragma unroll
    for (int j = 0; j < 4; j++) {
        float c  = cosp[s * HD + d0 + 2 * j];
        float sn = sinp[s * HD + d0 + 2 * j];
        float e0 = f[2 * j], e1 = f[2 * j + 1];
        f[2 * j]     = (e0 * c - e1 * sn) * scale;
        f[2 * j + 1] = (e1 * c + e0 * sn) * scale;
    }
    bf16x8 o;
#pragma unroll
    for (int j = 0; j < 8; j++) o[j] = (__bf16)f[j];
    *(bf16x8*)p = o;
}

// --------------- GEMM: C[M][N] = A[M][K] * Bt[N][K]^T  (bf16 MFMA) ----------
// 128x128 tile, BK=64, 4 waves (2x2 of 64x64), T2 XOR-swizzled LDS.
template <bool OUTF32>
__global__ __launch_bounds__(256) void k_gemm(const __bf16* __restrict__ A,
                                              const __bf16* __restrict__ Bt,
                                              void* __restrict__ Cp,
                                              int M, int N, int K) {
    (void)M;
    __shared__ __bf16 As[128 * 64];
    __shared__ __bf16 Bs[128 * 64];
    const int tid = threadIdx.x, lane = tid & 63, wave = tid >> 6;
    const int wm = wave >> 1, wn = wave & 1;
    const int m0 = blockIdx.x * 128, n0 = blockIdx.y * 128;
    const int lo = lane & 15, hi = lane >> 4;
    f32x4 acc[4][4] = {};

    const int srow = wave * 8 + (lane >> 3); // staging row (+ r*32)
    const int sp   = lane & 7;               // physical 16B chunk

    for (int kt = 0; kt < K; kt += 64) {
#pragma unroll
        for (int r = 0; r < 4; r++) {        // A tile: rows of A, contiguous K
            int row = r * 32 + srow;
            int c = sp ^ (row & 7);          // inverse-swizzled source chunk
            gld16(A + (size_t)(m0 + row) * K + kt + c * 8, &As[(r * 32 + wave * 8) * 64]);
        }
#pragma unroll
        for (int r = 0; r < 4; r++) {        // B tile: rows of Bt (= cols of B)
            int row = r * 32 + srow;
            int c = sp ^ (row & 7);
            gld16(Bt + (size_t)(n0 + row) * K + kt + c * 8, &Bs[(r * 32 + wave * 8) * 64]);
        }
        __syncthreads();
#pragma unroll
        for (int ks = 0; ks < 2; ks++) {
            bf16x8 af[4], bfr[4];
#pragma unroll
            for (int mt = 0; mt < 4; mt++) {
                int row = wm * 64 + mt * 16 + lo;
                int pp = (ks * 4 + hi) ^ (row & 7);
                af[mt] = *(const bf16x8*)&As[row * 64 + pp * 8];
            }
#pragma unroll
            for (int nt = 0; nt < 4; nt++) {
                int row = wn * 64 + nt * 16 + lo;
                int pp = (ks * 4 + hi) ^ (row & 7);
                bfr[nt] = *(const bf16x8*)&Bs[row * 64 + pp * 8];
            }
#pragma unroll
            for (int mt = 0; mt < 4; mt++)
#pragma unroll
                for (int nt = 0; nt < 4; nt++)
                    acc[mt][nt] = __builtin_amdgcn_mfma_f32_16x16x32_bf16(
                        af[mt], bfr[nt], acc[mt][nt], 0, 0, 0);
        }
        __syncthreads();
    }
    // epilogue: C/D layout col=lane&15, row=(lane>>4)*4+reg
#pragma unroll
    for (int mt = 0; mt < 4; mt++) {
#pragma unroll
        for (int nt = 0; nt < 4; nt++) {
            int row = m0 + wm * 64 + mt * 16 + hi * 4;
            int col = n0 + wn * 64 + nt * 16 + lo;
#pragma unroll
            for (int r = 0; r < 4; r++) {
                if (OUTF32)
                    ((float*)Cp)[(size_t)(row + r) * N + col] = acc[mt][nt][r];
                else
                    ((__bf16*)Cp)[(size_t)(row + r) * N + col] = (__bf16)acc[mt][nt][r];
            }
        }
    }
}

// ----------------------------- flash attention ------------------------------
// grid (pair=8, head=16, batch=4); block = 512 threads = 8 waves x 16 q-rows
// = 128 q-rows (QBLK=128). Each block does q-tiles {pair, 15-pair} -> uniform
// 34 kv-tile iterations. KVBLK=64; GQA /4; double-buffered K/V LDS.
// LDS = 2*16K (K) + 2*16K (V) + 8*2K (P) = 80 KB -> 2 blocks/CU = 16 waves/CU.
__global__ __launch_bounds__(512) void k_attn(const __bf16* __restrict__ qb,
                                              const __bf16* __restrict__ kb,
                                              const __bf16* __restrict__ vtb,
                                              __bf16* __restrict__ ob) {
    __shared__ __bf16 Ks[2][64 * 128];   // [kv][d]
    __shared__ __bf16 Vs[2][128 * 64];   // [d][kv]
    __shared__ __bf16 Ps[8][16 * 64];    // per-wave P
    const int tid = threadIdx.x, lane = tid & 63, wave = tid >> 6;
    const int pair = blockIdx.x, h = blockIdx.y, b = blockIdx.z;
    const int kvh = h >> 2;
    const int lo = lane & 15, hi = lane >> 4;

    const __bf16* kbb = kb + kvh * HD + (size_t)b * S_LEN * KVLD;
    const __bf16* vbb = vtb + (size_t)(b * NKV + kvh) * HD * S_LEN;

    // 8-wave staging: K tile [64][128] (16 chunks/row, 4 rows/wave/round),
    //                 V tile [128][64] (8 chunks/row, 8 rows/wave/round).
    const int krow_s = wave * 4 + (lane >> 4);  // + r*32
    const int kp_s   = lane & 15;
    const int vrow_s = wave * 8 + (lane >> 3);  // + r*64
    const int vp_s   = lane & 7;

    auto STAGE = [&](int buf, int t) {
#pragma unroll
        for (int r = 0; r < 2; r++) {
            int row = r * 32 + krow_s;
            int c = kp_s ^ (row & 7);
            gld16(kbb + (size_t)(t * 64 + row) * KVLD + c * 8,
                  &Ks[buf][(r * 32 + wave * 4) * 128]);
        }
#pragma unroll
        for (int r = 0; r < 2; r++) {
            int row = r * 64 + vrow_s;
            int c = vp_s ^ (row & 7);
            gld16(vbb + (size_t)row * S_LEN + t * 64 + c * 8,
                  &Vs[buf][(r * 64 + wave * 8) * 64]);
        }
    };

#pragma unroll 1
    for (int pi = 0; pi < 2; pi++) {
        const int qt = pi ? (NQT - 1 - pair) : pair;   // 128-row q-tile index
        const int nkv = 2 * qt + 2;                    // kv tiles of 64 rows

        // Q fragments (q is pre-scaled by 1/sqrt(HD) in k_rope)
        const int qrow = qt * 128 + wave * 16 + lo;
        const __bf16* qptr = qb + (size_t)(b * S_LEN + qrow) * HID + h * HD;
        bf16x8 qa[4];
#pragma unroll
        for (int kf = 0; kf < 4; kf++) qa[kf] = *(const bf16x8*)(qptr + kf * 32 + hi * 8);

        f32x4 o[8] = {};
        float Mr[4] = {-3e30f, -3e30f, -3e30f, -3e30f};
        float Lr[4] = {0.f, 0.f, 0.f, 0.f};

        int cur = 0;
        STAGE(0, 0);
        __syncthreads();   // drains stage-0 loads (compiler vmcnt(0) at barrier)

#pragma unroll 1
        for (int t = 0; t < nkv; t++) {
            if (t < nkv - 1) STAGE(cur ^ 1, t + 1);  // prefetch hides HBM latency

            // S = Q K^T  (rows = q, cols = kv)
            f32x4 sc[4];
#pragma unroll
            for (int nt = 0; nt < 4; nt++) {
                f32x4 s4 = {0.f, 0.f, 0.f, 0.f};
#pragma unroll
                for (int kf = 0; kf < 4; kf++) {
                    int row = nt * 16 + lo;
                    int pp = (kf * 4 + hi) ^ (row & 7);
                    bf16x8 kf8 = *(const bf16x8*)&Ks[cur][row * 128 + pp * 8];
                    s4 = __builtin_amdgcn_mfma_f32_16x16x32_bf16(qa[kf], kf8, s4, 0, 0, 0);
                }
                sc[nt] = s4;
            }
            if (t >= 2 * qt) { // causal mask only on tiles overlapping the q-range
#pragma unroll
                for (int nt = 0; nt < 4; nt++)
#pragma unroll
                    for (int r = 0; r < 4; r++) {
                        int qg = qt * 128 + wave * 16 + hi * 4 + r;
                        int kg = t * 64 + nt * 16 + lo;
                        if (kg > qg) sc[nt][r] = -1e30f;
                    }
            }
            // online softmax (fp32); row m = hi*4+r lives in a 16-lane group.
            // T13 defer-max: keep old running max if growth <= 8 (P bounded e^8).
            float p[4][4];
#pragma unroll
            for (int r = 0; r < 4; r++) {
                float m = fmaxf(fmaxf(sc[0][r], sc[1][r]), fmaxf(sc[2][r], sc[3][r]));
#pragma unroll
                for (int msk = 1; msk < 16; msk <<= 1) m = fmaxf(m, __shfl_xor(m, msk, 64));
                float mn = (m <= Mr[r] + 8.f) ? Mr[r] : m;
                float sum = 0.f;
#pragma unroll
                for (int nt = 0; nt < 4; nt++) {
                    float e = __expf(sc[nt][r] - mn);
                    p[nt][r] = e;
                    sum += e;
                }
#pragma unroll
                for (int msk = 1; msk < 16; msk <<= 1) sum += __shfl_xor(sum, msk, 64);
                if (mn != Mr[r]) {
                    float scl = __expf(Mr[r] - mn);
                    Lr[r] = Lr[r] * scl + sum;
                    Mr[r] = mn;
#pragma unroll
                    for (int dt = 0; dt < 8; dt++) o[dt][r] *= scl;
                } else {
                    Lr[r] += sum;
                }
            }
            // P (C-layout) -> wave-private swizzled LDS -> A-fragments
#pragma unroll
            for (int nt = 0; nt < 4; nt++)
#pragma unroll
                for (int r = 0; r < 4; r++) {
                    int m = hi * 4 + r;
                    int n = nt * 16 + lo;
                    int pp = (n >> 3) ^ (m & 7);
                    Ps[wave][m * 64 + pp * 8 + (n & 7)] = (__bf16)p[nt][r];
                }
            asm volatile("s_waitcnt lgkmcnt(0)" ::: "memory");
            // O += P V   (pa invariant across dt: hoist the 2 reads)
            bf16x8 pa[2];
#pragma unroll
            for (int sub = 0; sub < 2; sub++) {
                int ch = sub * 4 + hi;
                pa[sub] = *(const bf16x8*)&Ps[wave][lo * 64 + (ch ^ (lo & 7)) * 8];
            }
#pragma unroll
            for (int dt = 0; dt < 8; dt++) {
#pragma unroll
                for (int sub = 0; sub < 2; sub++) {
                    int ch = sub * 4 + hi;
                    int rowd = dt * 16 + lo;
                    bf16x8 vv = *(const bf16x8*)&Vs[cur][rowd * 64 + (ch ^ (rowd & 7)) * 8];
                    o[dt] = __builtin_amdgcn_mfma_f32_16x16x32_bf16(pa[sub], vv, o[dt], 0, 0, 0);
                }
            }
            __syncthreads();  // drains prefetch; protects K/V bufs before reuse
            cur ^= 1;
        }
        // epilogue: write O / L as bf16 into [b*S+q][h*HD+d]
        float rl[4];
#pragma unroll
        for (int r = 0; r < 4; r++) rl[r] = 1.0f / Lr[r];
#pragma unroll
        for (int dt = 0; dt < 8; dt++)
#pragma unroll
            for (int r = 0; r < 4; r++) {
                int qg = qt * 128 + wave * 16 + hi * 4 + r;
                int col = h * HD + dt * 16 + lo;
                ob[(size_t)(b * S_LEN + qg) * HID + col] = (__bf16)(o[dt][r] * rl[r]);
            }
    }
}

// ----------------------------------- host -----------------------------------
extern "C" void kernel_launch(void* const* d_in, const int* in_sizes, int n_in,
                              void* d_out, int out_size, void* d_ws, size_t ws_size,
                              hipStream_t stream) {
    (void)in_sizes; (void)n_in; (void)out_size; (void)ws_size;
    const float* x    = (const float*)d_in[0];
    const float* cosp = (const float*)d_in[1];
    const float* sinp = (const float*)d_in[2];
    const float* Wq   = (const float*)d_in[3];
    const float* Wk   = (const float*)d_in[4];
    const float* Wv   = (const float*)d_in[5];
    const float* Wo   = (const float*)d_in[6];
    float* out = (float*)d_out;

    char* ws = (char*)d_ws;
    __bf16* xb   = (__bf16*)(ws);                 // [8192][2048]        32 MB
    __bf16* wqt  = (__bf16*)(ws + 33554432);      // [2048][2048]         8 MB
    __bf16* wkvt = (__bf16*)(ws + 41943040);      // [1024][2048] (k|v)   4 MB
    __bf16* wot  = (__bf16*)(ws + 46137344);      // [2048][2048]         8 MB
    __bf16* qbuf = (__bf16*)(ws + 54525952);      // [8192][2048]        32 MB
    __bf16* kv   = (__bf16*)(ws + 88080384);      // [8192][1024]        16 MB
    __bf16* vtb  = (__bf16*)(ws + 104857600);     // [16][128][2048]      8 MB
    __bf16* aob  = xb;                            // reuse xb after QKV GEMMs

    k_conv_x<<<MTOT * HID / 8 / 256, 256, 0, stream>>>(x, xb);
    { dim3 g(32, 32); k_transpose_w<<<g, 256, 0, stream>>>(Wq, wqt, HID, HID); }
    { dim3 g(32, 8);  k_transpose_w<<<g, 256, 0, stream>>>(Wk, wkvt, HID, NKV * HD); }
    { dim3 g(32, 8);  k_transpose_w<<<g, 256, 0, stream>>>(Wv, wkvt + (size_t)512 * HID, HID, NKV * HD); }
    { dim3 g(32, 32); k_transpose_w<<<g, 256, 0, stream>>>(Wo, wot, HID, HID); }

    { dim3 g(MTOT / 128, HID / 128);  k_gemm<false><<<g, 256, 0, stream>>>(xb, wqt,  qbuf, MTOT, HID,  HID); }
    { dim3 g(MTOT / 128, KVLD / 128); k_gemm<false><<<g, 256, 0, stream>>>(xb, wkvt, kv,   MTOT, KVLD, HID); }

    k_rope<<<MTOT * HID / 8 / 256, 256, 0, stream>>>(qbuf, cosp, sinp, HID, HID / 8,
                                                     0.08838834764831845f); // 1/sqrt(128)
    k_rope<<<MTOT * 512 / 8 / 256, 256, 0, stream>>>(kv, cosp, sinp, KVLD, 512 / 8, 1.0f);

    { dim3 g(S_LEN / 64, HD / 64, 16); k_transpose_v<<<g, 256, 0, stream>>>(kv, vtb); }
    { dim3 g(NQT / 2, 16, BATCH);      k_attn<<<g, 512, 0, stream>>>(qbuf, kv, vtb, aob); }
    { dim3 g(MTOT / 128, HID / 128);   k_gemm<true><<<g, 256, 0, stream>>>(aob, wot, out, MTOT, HID, HID); }
}

// Round 4
// 437.266 us; speedup vs baseline: 1.4194x; 1.1547x over previous
//
#include <hip/hip_runtime.h>
#include <stdint.h>

#define S_LEN 2048
#define BATCH 4
#define HID   2048
#define HD    128
#define NKV   4
#define KVLD  1024          // combined K|V projection row stride (2*NKV*HD)
#define MTOT  (BATCH*S_LEN) // 8192
#define NQT   (S_LEN/128)   // 16 q-tiles (128 rows) per (b,h)

typedef float  f32x4  __attribute__((ext_vector_type(4)));
typedef __bf16 bf16x8 __attribute__((ext_vector_type(8)));
typedef __bf16 bf16x4 __attribute__((ext_vector_type(4)));

// async global->LDS, 16B per lane. LDS dest = wave-uniform base + lane*16.
__device__ __forceinline__ void gld16(const void* g, void* l) {
    __builtin_amdgcn_global_load_lds(
        (const __attribute__((address_space(1))) void*)g,
        (__attribute__((address_space(3))) void*)l, 16, 0, 0);
}

// ---------------- fp32 -> bf16 bulk convert (8 elems/thread) ----------------
__global__ void k_conv_x(const float* __restrict__ in, __bf16* __restrict__ out) {
    int i = blockIdx.x * blockDim.x + threadIdx.x;
    f32x4 a = ((const f32x4*)in)[2 * i];
    f32x4 b = ((const f32x4*)in)[2 * i + 1];
    bf16x8 o;
    o[0] = (__bf16)a[0]; o[1] = (__bf16)a[1]; o[2] = (__bf16)a[2]; o[3] = (__bf16)a[3];
    o[4] = (__bf16)b[0]; o[5] = (__bf16)b[1]; o[6] = (__bf16)b[2]; o[7] = (__bf16)b[3];
    ((bf16x8*)out)[i] = o;
}

// ------------- W [K][N] fp32 -> Wt [N][K] bf16 (64x64 LDS tiles) ------------
__global__ void k_transpose_w(const float* __restrict__ in, __bf16* __restrict__ out,
                              int K, int N) {
    __shared__ float tile[64][65];
    int k0 = blockIdx.x * 64, n0 = blockIdx.y * 64;
    for (int e = threadIdx.x; e < 4096; e += 256) {
        int r = e >> 6, c = e & 63;
        tile[r][c] = in[(size_t)(k0 + r) * N + n0 + c];
    }
    __syncthreads();
    for (int e = threadIdx.x; e < 4096; e += 256) {
        int r = e >> 6, c = e & 63;
        out[(size_t)(n0 + r) * K + k0 + c] = (__bf16)tile[c][r];
    }
}

// -------- V slice of kvbuf [8192][1024] -> vt [16 planes][128 d][2048 s] ----
__global__ void k_transpose_v(const __bf16* __restrict__ kv, __bf16* __restrict__ vt) {
    __shared__ __bf16 tile[64][65];
    int plane = blockIdx.z;          // b*NKV + kvh
    int b = plane >> 2, kvh = plane & 3;
    int s0 = blockIdx.x * 64, d0 = blockIdx.y * 64;
    const __bf16* src = kv + (size_t)(b * S_LEN + s0) * KVLD + NKV * HD + kvh * HD + d0;
    for (int e = threadIdx.x; e < 4096; e += 256) {
        int r = e >> 6, c = e & 63;            // r: s offset, c: d offset
        tile[r][c] = src[(size_t)r * KVLD + c];
    }
    __syncthreads();
    __bf16* dst = vt + (size_t)plane * HD * S_LEN + (size_t)d0 * S_LEN + s0;
    for (int e = threadIdx.x; e < 4096; e += 256) {
        int r = e >> 6, c = e & 63;            // r: d offset, c: s offset
        dst[(size_t)r * S_LEN + c] = tile[c][r];
    }
}

// -------------------- RoPE (interleaved pairs) + optional scale -------------
__global__ void k_rope(__bf16* __restrict__ buf, const float* __restrict__ cosp,
                       const float* __restrict__ sinp, int ld, int ncol8, float scale) {
    int i = blockIdx.x * blockDim.x + threadIdx.x;
    int row = i / ncol8;
    int c0 = (i % ncol8) * 8;
    int s = row & (S_LEN - 1);
    int d0 = c0 & (HD - 1);
    __bf16* p = buf + (size_t)row * ld + c0;
    bf16x8 v = *(const bf16x8*)p;
    float f[8];
#pragma unroll
    for (int j = 0; j < 8; j++) f[j] = (float)v[j];
#pragma unroll
    for (int j = 0; j < 4; j++) {
        float c  = cosp[s * HD + d0 + 2 * j];
        float sn = sinp[s * HD + d0 + 2 * j];
        float e0 = f[2 * j], e1 = f[2 * j + 1];
        f[2 * j]     = (e0 * c - e1 * sn) * scale;
        f[2 * j + 1] = (e1 * c + e0 * sn) * scale;
    }
    bf16x8 o;
#pragma unroll
    for (int j = 0; j < 8; j++) o[j] = (__bf16)f[j];
    *(bf16x8*)p = o;
}

// --------------- GEMM: C[M][N] = A[M][K] * Bt[N][K]^T  (bf16 MFMA) ----------
// 128x128 tile, BK=64, 4 waves (2x2 of 64x64), T2 XOR-swizzled LDS.
template <bool OUTF32>
__global__ __launch_bounds__(256) void k_gemm(const __bf16* __restrict__ A,
                                              const __bf16* __restrict__ Bt,
                                              void* __restrict__ Cp,
                                              int M, int N, int K) {
    (void)M;
    __shared__ __bf16 As[128 * 64];
    __shared__ __bf16 Bs[128 * 64];
    const int tid = threadIdx.x, lane = tid & 63, wave = tid >> 6;
    const int wm = wave >> 1, wn = wave & 1;
    const int m0 = blockIdx.x * 128, n0 = blockIdx.y * 128;
    const int lo = lane & 15, hi = lane >> 4;
    f32x4 acc[4][4] = {};

    const int srow = wave * 8 + (lane >> 3); // staging row (+ r*32)
    const int sp   = lane & 7;               // physical 16B chunk

    for (int kt = 0; kt < K; kt += 64) {
#pragma unroll
        for (int r = 0; r < 4; r++) {        // A tile: rows of A, contiguous K
            int row = r * 32 + srow;
            int c = sp ^ (row & 7);          // inverse-swizzled source chunk
            gld16(A + (size_t)(m0 + row) * K + kt + c * 8, &As[(r * 32 + wave * 8) * 64]);
        }
#pragma unroll
        for (int r = 0; r < 4; r++) {        // B tile: rows of Bt (= cols of B)
            int row = r * 32 + srow;
            int c = sp ^ (row & 7);
            gld16(Bt + (size_t)(n0 + row) * K + kt + c * 8, &Bs[(r * 32 + wave * 8) * 64]);
        }
        __syncthreads();
#pragma unroll
        for (int ks = 0; ks < 2; ks++) {
            bf16x8 af[4], bfr[4];
#pragma unroll
            for (int mt = 0; mt < 4; mt++) {
                int row = wm * 64 + mt * 16 + lo;
                int pp = (ks * 4 + hi) ^ (row & 7);
                af[mt] = *(const bf16x8*)&As[row * 64 + pp * 8];
            }
#pragma unroll
            for (int nt = 0; nt < 4; nt++) {
                int row = wn * 64 + nt * 16 + lo;
                int pp = (ks * 4 + hi) ^ (row & 7);
                bfr[nt] = *(const bf16x8*)&Bs[row * 64 + pp * 8];
            }
#pragma unroll
            for (int mt = 0; mt < 4; mt++)
#pragma unroll
                for (int nt = 0; nt < 4; nt++)
                    acc[mt][nt] = __builtin_amdgcn_mfma_f32_16x16x32_bf16(
                        af[mt], bfr[nt], acc[mt][nt], 0, 0, 0);
        }
        __syncthreads();
    }
    // epilogue: C/D layout col=lane&15, row=(lane>>4)*4+reg
#pragma unroll
    for (int mt = 0; mt < 4; mt++) {
#pragma unroll
        for (int nt = 0; nt < 4; nt++) {
            int row = m0 + wm * 64 + mt * 16 + hi * 4;
            int col = n0 + wn * 64 + nt * 16 + lo;
#pragma unroll
            for (int r = 0; r < 4; r++) {
                if (OUTF32)
                    ((float*)Cp)[(size_t)(row + r) * N + col] = acc[mt][nt][r];
                else
                    ((__bf16*)Cp)[(size_t)(row + r) * N + col] = (__bf16)acc[mt][nt][r];
            }
        }
    }
}

// ----------------------------- flash attention ------------------------------
// grid (pair=8, head=16, batch=4); block = 512 threads = 8 waves x 16 q-rows.
// Swapped QK^T: S^T = mfma(K,Q) -> lane holds 16 kv-scores for q=lane&15;
// softmax reduce = in-lane + 2 shfl_xor; Mr/Lr scalar per lane.
// PV: O^T = mfma(Vt, P). Epilogue transposes O^T via Ps for coalesced stores.
// LDS: K dbuf 2x16K + V single 16K + Ps 16K = 64 KB -> 2 blocks/CU.
__global__ __launch_bounds__(512) void k_attn(const __bf16* __restrict__ qb,
                                              const __bf16* __restrict__ kb,
                                              const __bf16* __restrict__ vtb,
                                              __bf16* __restrict__ ob) {
    __shared__ __bf16 Ks[2][64 * 128];   // [kv][d], XOR-swizzled rows
    __shared__ __bf16 Vs[128 * 64];      // [d][kv], XOR-swizzled rows (single buf)
    __shared__ __bf16 Ps[8][16 * 64];    // per-wave P^T->P transpose buffer
    const int tid = threadIdx.x, lane = tid & 63, wave = tid >> 6;
    const int pair = blockIdx.x, h = blockIdx.y, b = blockIdx.z;
    const int kvh = h >> 2;
    const int lo = lane & 15, hi = lane >> 4;
    char* PsW = (char*)&Ps[wave][0];

    const __bf16* kbb = kb + kvh * HD + (size_t)b * S_LEN * KVLD;
    const __bf16* vbb = vtb + (size_t)(b * NKV + kvh) * HD * S_LEN;

    const int krow_s = wave * 4 + (lane >> 4);  // + r*32
    const int kp_s   = lane & 15;
    const int vrow_s = wave * 8 + (lane >> 3);  // + r*64
    const int vp_s   = lane & 7;

    auto STAGE_K = [&](int buf, int t) {
#pragma unroll
        for (int r = 0; r < 2; r++) {
            int row = r * 32 + krow_s;
            int c = kp_s ^ (row & 7);
            gld16(kbb + (size_t)(t * 64 + row) * KVLD + c * 8,
                  &Ks[buf][(r * 32 + wave * 4) * 128]);
        }
    };
    auto STAGE_V = [&](int t) {
#pragma unroll
        for (int r = 0; r < 2; r++) {
            int row = r * 64 + vrow_s;
            int c = vp_s ^ (row & 7);
            gld16(vbb + (size_t)row * S_LEN + t * 64 + c * 8,
                  &Vs[(r * 64 + wave * 8) * 64]);
        }
    };

#pragma unroll 1
    for (int pi = 0; pi < 2; pi++) {
        const int qt = pi ? (NQT - 1 - pair) : pair;   // 128-row q-tile index
        const int nkv = 2 * qt + 2;                    // kv tiles of 64 rows

        // Q fragments (q pre-scaled by 1/sqrt(HD) in k_rope); q-row = lo
        const int qrow = qt * 128 + wave * 16 + lo;
        const __bf16* qptr = qb + (size_t)(b * S_LEN + qrow) * HID + h * HD;
        bf16x8 qa[4];
#pragma unroll
        for (int kf = 0; kf < 4; kf++) qa[kf] = *(const bf16x8*)(qptr + kf * 32 + hi * 8);

        f32x4 o[8] = {};                 // O^T: o[dt][r] = O[q=lo][d=dt*16+hi*4+r]
        float Mr = -3e30f, Lr = 0.f;     // scalar: this lane's q-row

        int cur = 0;
        STAGE_K(0, 0);
        STAGE_V(0);
        __syncthreads();

#pragma unroll 1
        for (int t = 0; t < nkv; t++) {
            if (t < nkv - 1) STAGE_K(cur ^ 1, t + 1);

            // S^T = K Q^T: sc[nt][r] = S[kv=t*64+nt*16+hi*4+r][q=lo]
            f32x4 sc[4];
            __builtin_amdgcn_s_setprio(1);
#pragma unroll
            for (int nt = 0; nt < 4; nt++) {
                f32x4 s4 = {0.f, 0.f, 0.f, 0.f};
#pragma unroll
                for (int kf = 0; kf < 4; kf++) {
                    int row = nt * 16 + lo;
                    int pp = (kf * 4 + hi) ^ (row & 7);
                    bf16x8 kf8 = *(const bf16x8*)&Ks[cur][row * 128 + pp * 8];
                    s4 = __builtin_amdgcn_mfma_f32_16x16x32_bf16(kf8, qa[kf], s4, 0, 0, 0);
                }
                sc[nt] = s4;
            }
            __builtin_amdgcn_s_setprio(0);

            if (t >= 2 * qt) { // causal mask on q-range-overlapping tiles
                int qg = qt * 128 + wave * 16 + lo;
#pragma unroll
                for (int nt = 0; nt < 4; nt++)
#pragma unroll
                    for (int r = 0; r < 4; r++) {
                        int kg = t * 64 + nt * 16 + hi * 4 + r;
                        if (kg > qg) sc[nt][r] = -1e30f;
                    }
            }
            // online softmax, in-lane + 2 shfl; T13 defer-max (thr=8)
            float mloc = sc[0][0];
#pragma unroll
            for (int nt = 0; nt < 4; nt++)
#pragma unroll
                for (int r = 0; r < 4; r++) mloc = fmaxf(mloc, sc[nt][r]);
            mloc = fmaxf(mloc, __shfl_xor(mloc, 16, 64));
            mloc = fmaxf(mloc, __shfl_xor(mloc, 32, 64));
            float mn = (mloc <= Mr + 8.f) ? Mr : mloc;
            float sum = 0.f;
#pragma unroll
            for (int nt = 0; nt < 4; nt++)
#pragma unroll
                for (int r = 0; r < 4; r++) {
                    float e = __expf(sc[nt][r] - mn);
                    sc[nt][r] = e;
                    sum += e;
                }
            sum += __shfl_xor(sum, 16, 64);
            sum += __shfl_xor(sum, 32, 64);
            if (mn != Mr) {
                float scl = __expf(Mr - mn);
                Lr = Lr * scl + sum;
                Mr = mn;
#pragma unroll
                for (int dt = 0; dt < 8; dt++) o[dt] *= scl;
            } else {
                Lr += sum;
            }
            // P write: lane holds P[kv=16nt+4hi+r][q=lo] -> Ps[q][kv] b64 packed
#pragma unroll
            for (int nt = 0; nt < 4; nt++) {
                bf16x4 pk;
#pragma unroll
                for (int r = 0; r < 4; r++) pk[r] = (__bf16)sc[nt][r];
                *(bf16x4*)(PsW + lo * 128 + ((nt * 32 + hi * 8) ^ ((lo & 7) << 4))) = pk;
            }
            __syncthreads();  // A: drains V[t] + K[t+1] stages; orders P writes

            // O^T += V^T P : A-frag = Vs row d, B-frag = Ps row q
            __builtin_amdgcn_s_setprio(1);
            bf16x8 pf[2];
#pragma unroll
            for (int c = 0; c < 2; c++)
                pf[c] = *(const bf16x8*)(PsW + lo * 128 + ((c * 64 + hi * 16) ^ ((lo & 7) << 4)));
#pragma unroll
            for (int dt = 0; dt < 8; dt++) {
                int rowd = dt * 16 + lo;
#pragma unroll
                for (int c = 0; c < 2; c++) {
                    int ch = c * 4 + hi;
                    bf16x8 vv = *(const bf16x8*)&Vs[rowd * 64 + (ch ^ (rowd & 7)) * 8];
                    o[dt] = __builtin_amdgcn_mfma_f32_16x16x32_bf16(vv, pf[c], o[dt], 0, 0, 0);
                }
            }
            __builtin_amdgcn_s_setprio(0);
            __syncthreads();  // B: all waves done reading Vs
            if (t < nkv - 1) STAGE_V(t + 1);
            cur ^= 1;
        }
        // epilogue: O^T -> Ps (per-wave) -> coalesced bf16x8 stores, 2 halves
        float rl = 1.0f / Lr;
        const int qe = lane >> 2, c4 = lane & 3;
#pragma unroll
        for (int h2 = 0; h2 < 2; h2++) {
#pragma unroll
            for (int dt4 = 0; dt4 < 4; dt4++) {
                bf16x4 w;
#pragma unroll
                for (int r = 0; r < 4; r++) w[r] = (__bf16)(o[h2 * 4 + dt4][r] * rl);
                *(bf16x4*)(PsW + lo * 128 + ((dt4 * 32 + hi * 8) ^ ((lo & 7) << 4))) = w;
            }
            asm volatile("s_waitcnt lgkmcnt(0)" ::: "memory");
            __builtin_amdgcn_sched_barrier(0);
#pragma unroll
            for (int s2 = 0; s2 < 2; s2++) {
                int ch = c4 + s2 * 4;
                bf16x8 v = *(const bf16x8*)(PsW + qe * 128 + ((ch * 16) ^ ((qe & 7) << 4)));
                int qg = qt * 128 + wave * 16 + qe;
                int col = h * HD + h2 * 64 + ch * 8;
                *(bf16x8*)&ob[(size_t)(b * S_LEN + qg) * HID + col] = v;
            }
        }
    }
}

// ----------------------------------- host -----------------------------------
extern "C" void kernel_launch(void* const* d_in, const int* in_sizes, int n_in,
                              void* d_out, int out_size, void* d_ws, size_t ws_size,
                              hipStream_t stream) {
    (void)in_sizes; (void)n_in; (void)out_size; (void)ws_size;
    const float* x    = (const float*)d_in[0];
    const float* cosp = (const float*)d_in[1];
    const float* sinp = (const float*)d_in[2];
    const float* Wq   = (const float*)d_in[3];
    const float* Wk   = (const float*)d_in[4];
    const float* Wv   = (const float*)d_in[5];
    const float* Wo   = (const float*)d_in[6];
    float* out = (float*)d_out;

    char* ws = (char*)d_ws;
    __bf16* xb   = (__bf16*)(ws);                 // [8192][2048]        32 MB
    __bf16* wqt  = (__bf16*)(ws + 33554432);      // [2048][2048]         8 MB
    __bf16* wkvt = (__bf16*)(ws + 41943040);      // [1024][2048] (k|v)   4 MB
    __bf16* wot  = (__bf16*)(ws + 46137344);      // [2048][2048]         8 MB
    __bf16* qbuf = (__bf16*)(ws + 54525952);      // [8192][2048]        32 MB
    __bf16* kv   = (__bf16*)(ws + 88080384);      // [8192][1024]        16 MB
    __bf16* vtb  = (__bf16*)(ws + 104857600);     // [16][128][2048]      8 MB
    __bf16* aob  = xb;                            // reuse xb after QKV GEMMs

    k_conv_x<<<MTOT * HID / 8 / 256, 256, 0, stream>>>(x, xb);
    { dim3 g(32, 32); k_transpose_w<<<g, 256, 0, stream>>>(Wq, wqt, HID, HID); }
    { dim3 g(32, 8);  k_transpose_w<<<g, 256, 0, stream>>>(Wk, wkvt, HID, NKV * HD); }
    { dim3 g(32, 8);  k_transpose_w<<<g, 256, 0, stream>>>(Wv, wkvt + (size_t)512 * HID, HID, NKV * HD); }
    { dim3 g(32, 32); k_transpose_w<<<g, 256, 0, stream>>>(Wo, wot, HID, HID); }

    { dim3 g(MTOT / 128, HID / 128);  k_gemm<false><<<g, 256, 0, stream>>>(xb, wqt,  qbuf, MTOT, HID,  HID); }
    { dim3 g(MTOT / 128, KVLD / 128); k_gemm<false><<<g, 256, 0, stream>>>(xb, wkvt, kv,   MTOT, KVLD, HID); }

    k_rope<<<MTOT * HID / 8 / 256, 256, 0, stream>>>(qbuf, cosp, sinp, HID, HID / 8,
                                                     0.08838834764831845f); // 1/sqrt(128)
    k_rope<<<MTOT * 512 / 8 / 256, 256, 0, stream>>>(kv, cosp, sinp, KVLD, 512 / 8, 1.0f);

    { dim3 g(S_LEN / 64, HD / 64, 16); k_transpose_v<<<g, 256, 0, stream>>>(kv, vtb); }
    { dim3 g(NQT / 2, 16, BATCH);      k_attn<<<g, 512, 0, stream>>>(qbuf, kv, vtb, aob); }
    { dim3 g(MTOT / 128, HID / 128);   k_gemm<true><<<g, 256, 0, stream>>>(aob, wot, out, MTOT, HID, HID); }
}

// Round 5
// 436.840 us; speedup vs baseline: 1.4208x; 1.0010x over previous
//
#include <hip/hip_runtime.h>
#include <stdint.h>

#define S_LEN 2048
#define BATCH 4
#define HID   2048
#define HD    128
#define NKV   4
#define KVLD  1024          // combined K|V projection row stride (2*NKV*HD)
#define MTOT  (BATCH*S_LEN) // 8192
#define NQT   (S_LEN/128)   // 16 q-tiles (128 rows) per (b,h)
#define QSCALE 0.08838834764831845f

typedef float    f32x4  __attribute__((ext_vector_type(4)));
typedef __bf16   bf16x8 __attribute__((ext_vector_type(8)));
typedef __bf16   bf16x4 __attribute__((ext_vector_type(4)));
typedef unsigned u32x4  __attribute__((ext_vector_type(4)));

// async global->LDS, 16B per lane. LDS dest = wave-uniform base + lane*16.
__device__ __forceinline__ void gld16(const void* g, void* l) {
    __builtin_amdgcn_global_load_lds(
        (const __attribute__((address_space(1))) void*)g,
        (__attribute__((address_space(3))) void*)l, 16, 0, 0);
}

// pack two f32 -> u32 of 2 bf16 (element 0 in low half)
__device__ __forceinline__ unsigned pk2(float x, float y) {
    union { __bf16 h[2]; unsigned u; } t;
    t.h[0] = (__bf16)x; t.h[1] = (__bf16)y;
    return t.u;
}

// ---------------- fp32 -> bf16 bulk convert (8 elems/thread) ----------------
__global__ void k_conv_x(const float* __restrict__ in, __bf16* __restrict__ out) {
    int i = blockIdx.x * blockDim.x + threadIdx.x;
    f32x4 a = ((const f32x4*)in)[2 * i];
    f32x4 b = ((const f32x4*)in)[2 * i + 1];
    bf16x8 o;
    o[0] = (__bf16)a[0]; o[1] = (__bf16)a[1]; o[2] = (__bf16)a[2]; o[3] = (__bf16)a[3];
    o[4] = (__bf16)b[0]; o[5] = (__bf16)b[1]; o[6] = (__bf16)b[2]; o[7] = (__bf16)b[3];
    ((bf16x8*)out)[i] = o;
}

// ------------- W [K][N] fp32 -> Wt [N][K] bf16 (64x64 LDS tiles) ------------
__global__ void k_transpose_w(const float* __restrict__ in, __bf16* __restrict__ out,
                              int K, int N) {
    __shared__ float tile[64][65];
    int k0 = blockIdx.x * 64, n0 = blockIdx.y * 64;
    for (int e = threadIdx.x; e < 4096; e += 256) {
        int r = e >> 6, c = e & 63;
        tile[r][c] = in[(size_t)(k0 + r) * N + n0 + c];
    }
    __syncthreads();
    for (int e = threadIdx.x; e < 4096; e += 256) {
        int r = e >> 6, c = e & 63;
        out[(size_t)(n0 + r) * K + k0 + c] = (__bf16)tile[c][r];
    }
}

// -------- V slice of kvbuf [8192][1024] -> vt [16 planes][128 d][2048 s] ----
__global__ void k_transpose_v(const __bf16* __restrict__ kv, __bf16* __restrict__ vt) {
    __shared__ __bf16 tile[64][65];
    int plane = blockIdx.z;          // b*NKV + kvh
    int b = plane >> 2, kvh = plane & 3;
    int s0 = blockIdx.x * 64, d0 = blockIdx.y * 64;
    const __bf16* src = kv + (size_t)(b * S_LEN + s0) * KVLD + NKV * HD + kvh * HD + d0;
    for (int e = threadIdx.x; e < 4096; e += 256) {
        int r = e >> 6, c = e & 63;            // r: s offset, c: d offset
        tile[r][c] = src[(size_t)r * KVLD + c];
    }
    __syncthreads();
    __bf16* dst = vt + (size_t)plane * HD * S_LEN + (size_t)d0 * S_LEN + s0;
    for (int e = threadIdx.x; e < 4096; e += 256) {
        int r = e >> 6, c = e & 63;            // r: d offset, c: s offset
        dst[(size_t)r * S_LEN + c] = tile[c][r];
    }
}

// ---- merged QKV GEMM: C[8192][3072] = xb * [wqt|wkvt]^T, RoPE fused --------
// 128x128 tile, BK=64, 4 waves (2x2 of 64x64), XOR-swizzled LDS.
// cols [0,2048) -> q (rope + 1/sqrt(HD) scale) -> qbuf
// cols [2048,2560) -> k (rope) -> kv[:, 0:512)
// cols [2560,3072) -> v (plain) -> kv[:, 512:1024)
__global__ __launch_bounds__(256) void k_gemm_qkv(const __bf16* __restrict__ A,
                                                  const __bf16* __restrict__ Bt,
                                                  __bf16* __restrict__ qbuf,
                                                  __bf16* __restrict__ kvbuf,
                                                  const float* __restrict__ cosp,
                                                  const float* __restrict__ sinp) {
    __shared__ __bf16 As[128 * 64];
    __shared__ __bf16 Bs[128 * 64];
    const int tid = threadIdx.x, lane = tid & 63, wave = tid >> 6;
    const int wm = wave >> 1, wn = wave & 1;
    const int m0 = blockIdx.x * 128, n0 = blockIdx.y * 128;
    const int lo = lane & 15, hi = lane >> 4;
    f32x4 acc[4][4] = {};

    const int srow = wave * 8 + (lane >> 3); // staging row (+ r*32)
    const int sp   = lane & 7;               // physical 16B chunk

    for (int kt = 0; kt < HID; kt += 64) {
#pragma unroll
        for (int r = 0; r < 4; r++) {        // A tile
            int row = r * 32 + srow;
            int c = sp ^ (row & 7);
            gld16(A + (size_t)(m0 + row) * HID + kt + c * 8, &As[(r * 32 + wave * 8) * 64]);
        }
#pragma unroll
        for (int r = 0; r < 4; r++) {        // B tile
            int row = r * 32 + srow;
            int c = sp ^ (row & 7);
            gld16(Bt + (size_t)(n0 + row) * HID + kt + c * 8, &Bs[(r * 32 + wave * 8) * 64]);
        }
        __syncthreads();
#pragma unroll
        for (int ks = 0; ks < 2; ks++) {
            bf16x8 af[4], bfr[4];
#pragma unroll
            for (int mt = 0; mt < 4; mt++) {
                int row = wm * 64 + mt * 16 + lo;
                int pp = (ks * 4 + hi) ^ (row & 7);
                af[mt] = *(const bf16x8*)&As[row * 64 + pp * 8];
            }
#pragma unroll
            for (int nt = 0; nt < 4; nt++) {
                int row = wn * 64 + nt * 16 + lo;
                int pp = (ks * 4 + hi) ^ (row & 7);
                bfr[nt] = *(const bf16x8*)&Bs[row * 64 + pp * 8];
            }
#pragma unroll
            for (int mt = 0; mt < 4; mt++)
#pragma unroll
                for (int nt = 0; nt < 4; nt++)
                    acc[mt][nt] = __builtin_amdgcn_mfma_f32_16x16x32_bf16(
                        af[mt], bfr[nt], acc[mt][nt], 0, 0, 0);
        }
        __syncthreads();
    }
    // epilogue: rope via shfl_xor(1) pair exchange, then route q/k/v
    const float sgn = (lo & 1) ? 1.f : -1.f;
#pragma unroll
    for (int mt = 0; mt < 4; mt++) {
#pragma unroll
        for (int nt = 0; nt < 4; nt++) {
            int rowb = m0 + wm * 64 + mt * 16 + hi * 4;
            int colb = n0 + wn * 64 + nt * 16;
            int col = colb + lo;
            bool isQ = colb < 2048;
            bool doRope = colb < 2560;
            int d = col & (HD - 1);
#pragma unroll
            for (int r = 0; r < 4; r++) {
                float a = acc[mt][nt][r];
                float pv = __shfl_xor(a, 1, 64);
                if (doRope) {
                    int s = (rowb + r) & (S_LEN - 1);
                    float c = cosp[s * HD + d], sn = sinp[s * HD + d];
                    a = a * c + sgn * pv * sn;
                    if (isQ) a *= QSCALE;
                }
                if (isQ) qbuf[(size_t)(rowb + r) * HID + col] = (__bf16)a;
                else     kvbuf[(size_t)(rowb + r) * KVLD + (col - 2048)] = (__bf16)a;
            }
        }
    }
}

// --------------- GEMM: C[M][N] = A[M][K] * Bt[N][K]^T  (bf16 MFMA) ----------
template <bool OUTF32>
__global__ __launch_bounds__(256) void k_gemm(const __bf16* __restrict__ A,
                                              const __bf16* __restrict__ Bt,
                                              void* __restrict__ Cp,
                                              int M, int N, int K) {
    (void)M;
    __shared__ __bf16 As[128 * 64];
    __shared__ __bf16 Bs[128 * 64];
    const int tid = threadIdx.x, lane = tid & 63, wave = tid >> 6;
    const int wm = wave >> 1, wn = wave & 1;
    const int m0 = blockIdx.x * 128, n0 = blockIdx.y * 128;
    const int lo = lane & 15, hi = lane >> 4;
    f32x4 acc[4][4] = {};

    const int srow = wave * 8 + (lane >> 3);
    const int sp   = lane & 7;

    for (int kt = 0; kt < K; kt += 64) {
#pragma unroll
        for (int r = 0; r < 4; r++) {
            int row = r * 32 + srow;
            int c = sp ^ (row & 7);
            gld16(A + (size_t)(m0 + row) * K + kt + c * 8, &As[(r * 32 + wave * 8) * 64]);
        }
#pragma unroll
        for (int r = 0; r < 4; r++) {
            int row = r * 32 + srow;
            int c = sp ^ (row & 7);
            gld16(Bt + (size_t)(n0 + row) * K + kt + c * 8, &Bs[(r * 32 + wave * 8) * 64]);
        }
        __syncthreads();
#pragma unroll
        for (int ks = 0; ks < 2; ks++) {
            bf16x8 af[4], bfr[4];
#pragma unroll
            for (int mt = 0; mt < 4; mt++) {
                int row = wm * 64 + mt * 16 + lo;
                int pp = (ks * 4 + hi) ^ (row & 7);
                af[mt] = *(const bf16x8*)&As[row * 64 + pp * 8];
            }
#pragma unroll
            for (int nt = 0; nt < 4; nt++) {
                int row = wn * 64 + nt * 16 + lo;
                int pp = (ks * 4 + hi) ^ (row & 7);
                bfr[nt] = *(const bf16x8*)&Bs[row * 64 + pp * 8];
            }
#pragma unroll
            for (int mt = 0; mt < 4; mt++)
#pragma unroll
                for (int nt = 0; nt < 4; nt++)
                    acc[mt][nt] = __builtin_amdgcn_mfma_f32_16x16x32_bf16(
                        af[mt], bfr[nt], acc[mt][nt], 0, 0, 0);
        }
        __syncthreads();
    }
#pragma unroll
    for (int mt = 0; mt < 4; mt++) {
#pragma unroll
        for (int nt = 0; nt < 4; nt++) {
            int row = m0 + wm * 64 + mt * 16 + hi * 4;
            int col = n0 + wn * 64 + nt * 16 + lo;
#pragma unroll
            for (int r = 0; r < 4; r++) {
                if (OUTF32)
                    ((float*)Cp)[(size_t)(row + r) * N + col] = acc[mt][nt][r];
                else
                    ((__bf16*)Cp)[(size_t)(row + r) * N + col] = (__bf16)acc[mt][nt][r];
            }
        }
    }
}

// ----------------------------- flash attention ------------------------------
// grid (pair=8, head=16, batch=4); block = 512 threads = 8 waves x 16 q-rows.
// Swapped QK^T: lane holds 16 kv-scores for q=lane&15; softmax in-lane + 2 shfl.
// P stays IN REGISTERS: PV B-frag built via pack + 6 shfl_xor per 32-kv chunk
// (4-lane redistribution among {lo, lo+16, lo+32, lo+48}).
// K and V both double-buffered; ONE barrier per kv-tile.
// LDS: K 2x16K + V 2x16K = 64 KB. Epilogue reuses Ks[0] as transpose scratch.
__global__ __launch_bounds__(512) void k_attn(const __bf16* __restrict__ qb,
                                              const __bf16* __restrict__ kb,
                                              const __bf16* __restrict__ vtb,
                                              __bf16* __restrict__ ob) {
    __shared__ __bf16 Ks[2][64 * 128];   // [kv][d], XOR-swizzled rows
    __shared__ __bf16 Vs[2][128 * 64];   // [d][kv], XOR-swizzled rows
    const int tid = threadIdx.x, lane = tid & 63, wave = tid >> 6;
    const int pair = blockIdx.x, h = blockIdx.y, b = blockIdx.z;
    const int kvh = h >> 2;
    const int lo = lane & 15, hi = lane >> 4;
    char* PsW = (char*)&Ks[0][0] + wave * 2048;   // epilogue scratch only

    const __bf16* kbb = kb + kvh * HD + (size_t)b * S_LEN * KVLD;
    const __bf16* vbb = vtb + (size_t)(b * NKV + kvh) * HD * S_LEN;

    const int krow_s = wave * 4 + (lane >> 4);  // + r*32
    const int kp_s   = lane & 15;
    const int vrow_s = wave * 8 + (lane >> 3);  // + r*64
    const int vp_s   = lane & 7;

    auto STAGE_K = [&](int buf, int t) {
#pragma unroll
        for (int r = 0; r < 2; r++) {
            int row = r * 32 + krow_s;
            int c = kp_s ^ (row & 7);
            gld16(kbb + (size_t)(t * 64 + row) * KVLD + c * 8,
                  &Ks[buf][(r * 32 + wave * 4) * 128]);
        }
    };
    auto STAGE_V = [&](int buf, int t) {
#pragma unroll
        for (int r = 0; r < 2; r++) {
            int row = r * 64 + vrow_s;
            int c = vp_s ^ (row & 7);
            gld16(vbb + (size_t)row * S_LEN + t * 64 + c * 8,
                  &Vs[buf][(r * 64 + wave * 8) * 64]);
        }
    };

#pragma unroll 1
    for (int pi = 0; pi < 2; pi++) {
        const int qt = pi ? (NQT - 1 - pair) : pair;   // 128-row q-tile index
        const int nkv = 2 * qt + 2;                    // kv tiles of 64 rows

        __syncthreads();   // protect Ks[0] (epilogue scratch) before restaging

        // Q fragments (q pre-scaled by 1/sqrt(HD) in GEMM epilogue); q-row = lo
        const int qrow = qt * 128 + wave * 16 + lo;
        const __bf16* qptr = qb + (size_t)(b * S_LEN + qrow) * HID + h * HD;
        bf16x8 qa[4];
#pragma unroll
        for (int kf = 0; kf < 4; kf++) qa[kf] = *(const bf16x8*)(qptr + kf * 32 + hi * 8);

        f32x4 o[8] = {};                 // O^T: o[dt][r] = O[q=lo][d=dt*16+hi*4+r]
        float Mr = -3e30f, Lr = 0.f;

        int cur = 0;
        STAGE_K(0, 0);
        STAGE_V(0, 0);
        __syncthreads();

#pragma unroll 1
        for (int t = 0; t < nkv; t++) {
            if (t < nkv - 1) { STAGE_K(cur ^ 1, t + 1); STAGE_V(cur ^ 1, t + 1); }

            // S^T = K Q^T: sc[nt][r] = S[kv=t*64+nt*16+hi*4+r][q=lo]
            f32x4 sc[4];
            __builtin_amdgcn_s_setprio(1);
#pragma unroll
            for (int nt = 0; nt < 4; nt++) {
                f32x4 s4 = {0.f, 0.f, 0.f, 0.f};
#pragma unroll
                for (int kf = 0; kf < 4; kf++) {
                    int row = nt * 16 + lo;
                    int pp = (kf * 4 + hi) ^ (row & 7);
                    bf16x8 kf8 = *(const bf16x8*)&Ks[cur][row * 128 + pp * 8];
                    s4 = __builtin_amdgcn_mfma_f32_16x16x32_bf16(kf8, qa[kf], s4, 0, 0, 0);
                }
                sc[nt] = s4;
            }
            __builtin_amdgcn_s_setprio(0);

            if (t >= 2 * qt) { // causal mask on q-range-overlapping tiles
                int qg = qt * 128 + wave * 16 + lo;
#pragma unroll
                for (int nt = 0; nt < 4; nt++)
#pragma unroll
                    for (int r = 0; r < 4; r++) {
                        int kg = t * 64 + nt * 16 + hi * 4 + r;
                        if (kg > qg) sc[nt][r] = -1e30f;
                    }
            }
            // online softmax, in-lane + 2 shfl; T13 defer-max (thr=8)
            float mloc = sc[0][0];
#pragma unroll
            for (int nt = 0; nt < 4; nt++)
#pragma unroll
                for (int r = 0; r < 4; r++) mloc = fmaxf(mloc, sc[nt][r]);
            mloc = fmaxf(mloc, __shfl_xor(mloc, 16, 64));
            mloc = fmaxf(mloc, __shfl_xor(mloc, 32, 64));
            float mn = (mloc <= Mr + 8.f) ? Mr : mloc;
            float sum = 0.f;
#pragma unroll
            for (int nt = 0; nt < 4; nt++)
#pragma unroll
                for (int r = 0; r < 4; r++) {
                    float e = __expf(sc[nt][r] - mn);
                    sc[nt][r] = e;
                    sum += e;
                }
            sum += __shfl_xor(sum, 16, 64);
            sum += __shfl_xor(sum, 32, 64);
            if (mn != Mr) {
                float scl = __expf(Mr - mn);
                Lr = Lr * scl + sum;
                Mr = mn;
#pragma unroll
                for (int dt = 0; dt < 8; dt++) o[dt] *= scl;
            } else {
                Lr += sum;
            }
            // In-register P -> PV B-fragments. Lane holds P[kv=nt*16+hi*4+r][q=lo];
            // B-frag for chunk c needs P[kv=c*32+hi*8+j][q=lo], j=0..7:
            // a 4-lane redistribution among {lo, lo+16k}. pack + xor32 + xor16.
            bf16x8 pf[2];
#pragma unroll
            for (int c = 0; c < 2; c++) {
                unsigned a0 = pk2(sc[2 * c][0], sc[2 * c][1]);
                unsigned a1 = pk2(sc[2 * c][2], sc[2 * c][3]);
                unsigned b0 = pk2(sc[2 * c + 1][0], sc[2 * c + 1][1]);
                unsigned b1 = pk2(sc[2 * c + 1][2], sc[2 * c + 1][3]);
                unsigned ra0 = __shfl_xor((int)a0, 32, 64);
                unsigned ra1 = __shfl_xor((int)a1, 32, 64);
                unsigned rb0 = __shfl_xor((int)b0, 32, 64);
                unsigned rb1 = __shfl_xor((int)b1, 32, 64);
                unsigned x0 = (hi < 2) ? ((hi & 1) ? a0 : ra0) : ((hi & 1) ? rb0 : b0);
                unsigned x1 = (hi < 2) ? ((hi & 1) ? a1 : ra1) : ((hi & 1) ? rb1 : b1);
                unsigned y0 = __shfl_xor((int)x0, 16, 64);
                unsigned y1 = __shfl_xor((int)x1, 16, 64);
                u32x4 fv;
                fv[0] = (hi == 0) ? a0 : (hi == 2) ? rb0 : y0;
                fv[1] = (hi == 0) ? a1 : (hi == 2) ? rb1 : y1;
                fv[2] = (hi == 1) ? ra0 : (hi == 3) ? b0 : y0;
                fv[3] = (hi == 1) ? ra1 : (hi == 3) ? b1 : y1;
                pf[c] = __builtin_bit_cast(bf16x8, fv);
            }
            // O^T += V^T P
            __builtin_amdgcn_s_setprio(1);
#pragma unroll
            for (int dt = 0; dt < 8; dt++) {
                int rowd = dt * 16 + lo;
#pragma unroll
                for (int c = 0; c < 2; c++) {
                    int ch = c * 4 + hi;
                    bf16x8 vv = *(const bf16x8*)&Vs[cur][rowd * 64 + (ch ^ (rowd & 7)) * 8];
                    o[dt] = __builtin_amdgcn_mfma_f32_16x16x32_bf16(vv, pf[c], o[dt], 0, 0, 0);
                }
            }
            __builtin_amdgcn_s_setprio(0);
            __syncthreads();  // drains prefetch; protects both bufs before reuse
            cur ^= 1;
        }
        // epilogue: O^T -> scratch (Ks[0] area) -> coalesced bf16x8 stores
        float rl = 1.0f / Lr;
        const int qe = lane >> 2, c4 = lane & 3;
#pragma unroll
        for (int h2 = 0; h2 < 2; h2++) {
#pragma unroll
            for (int dt4 = 0; dt4 < 4; dt4++) {
                bf16x4 w;
#pragma unroll
                for (int r = 0; r < 4; r++) w[r] = (__bf16)(o[h2 * 4 + dt4][r] * rl);
                *(bf16x4*)(PsW + lo * 128 + ((dt4 * 32 + hi * 8) ^ ((lo & 7) << 4))) = w;
            }
            asm volatile("s_waitcnt lgkmcnt(0)" ::: "memory");
            __builtin_amdgcn_sched_barrier(0);
#pragma unroll
            for (int s2 = 0; s2 < 2; s2++) {
                int ch = c4 + s2 * 4;
                bf16x8 v = *(const bf16x8*)(PsW + qe * 128 + ((ch * 16) ^ ((qe & 7) << 4)));
                int qg = qt * 128 + wave * 16 + qe;
                int col = h * HD + h2 * 64 + ch * 8;
                *(bf16x8*)&ob[(size_t)(b * S_LEN + qg) * HID + col] = v;
            }
        }
    }
}

// ----------------------------------- host -----------------------------------
extern "C" void kernel_launch(void* const* d_in, const int* in_sizes, int n_in,
                              void* d_out, int out_size, void* d_ws, size_t ws_size,
                              hipStream_t stream) {
    (void)in_sizes; (void)n_in; (void)out_size; (void)ws_size;
    const float* x    = (const float*)d_in[0];
    const float* cosp = (const float*)d_in[1];
    const float* sinp = (const float*)d_in[2];
    const float* Wq   = (const float*)d_in[3];
    const float* Wk   = (const float*)d_in[4];
    const float* Wv   = (const float*)d_in[5];
    const float* Wo   = (const float*)d_in[6];
    float* out = (float*)d_out;

    char* ws = (char*)d_ws;
    __bf16* xb   = (__bf16*)(ws);                 // [8192][2048]        32 MB
    __bf16* wqt  = (__bf16*)(ws + 33554432);      // [2048][2048]         8 MB
    __bf16* wkvt = (__bf16*)(ws + 41943040);      // [1024][2048] (k|v)   4 MB  (contiguous with wqt -> [3072][2048])
    __bf16* wot  = (__bf16*)(ws + 46137344);      // [2048][2048]         8 MB
    __bf16* qbuf = (__bf16*)(ws + 54525952);      // [8192][2048]        32 MB
    __bf16* kv   = (__bf16*)(ws + 88080384);      // [8192][1024]        16 MB
    __bf16* vtb  = (__bf16*)(ws + 104857600);     // [16][128][2048]      8 MB
    __bf16* aob  = xb;                            // reuse xb after QKV GEMM

    k_conv_x<<<MTOT * HID / 8 / 256, 256, 0, stream>>>(x, xb);
    { dim3 g(32, 32); k_transpose_w<<<g, 256, 0, stream>>>(Wq, wqt, HID, HID); }
    { dim3 g(32, 8);  k_transpose_w<<<g, 256, 0, stream>>>(Wk, wkvt, HID, NKV * HD); }
    { dim3 g(32, 8);  k_transpose_w<<<g, 256, 0, stream>>>(Wv, wkvt + (size_t)512 * HID, HID, NKV * HD); }
    { dim3 g(32, 32); k_transpose_w<<<g, 256, 0, stream>>>(Wo, wot, HID, HID); }

    { dim3 g(MTOT / 128, 3072 / 128);
      k_gemm_qkv<<<g, 256, 0, stream>>>(xb, wqt, qbuf, kv, cosp, sinp); }

    { dim3 g(S_LEN / 64, HD / 64, 16); k_transpose_v<<<g, 256, 0, stream>>>(kv, vtb); }
    { dim3 g(NQT / 2, 16, BATCH);      k_attn<<<g, 512, 0, stream>>>(qbuf, kv, vtb, aob); }
    { dim3 g(MTOT / 128, HID / 128);   k_gemm<true><<<g, 256, 0, stream>>>(aob, wot, out, MTOT, HID, HID); }
}